// Round 6
// baseline (321.769 us; speedup 1.0000x reference)
//
#include <hip/hip_runtime.h>
#include <hip/hip_bf16.h>
#include <math.h>

typedef __hip_bfloat16 bf16;
typedef __attribute__((ext_vector_type(4))) float f32x4;
typedef __attribute__((ext_vector_type(8))) short s16x8;

#define NB 8192
#define KP 1152   // padded K: 1089 -> 36*32
#define NP 1152   // padded N: 1089 -> 9*128
#define NK 36     // KP/32

// Packed fragment layouts (verified by round-5 pass; re-indexed for 16-row granularity):
// pA 16B unit: ((ks*512 + m16)*64 + q*16 + fr) holds A[m16*16+fr][ks*32+q*8 .. +7]
// pB 16B unit: ((ks*72  + fn )*64 + q*16 + fr) holds B[fn*16+fr][ks*32+q*8 .. +7]
// A wave frag load = base + lane*16B -> one coalesced 1KB dwordx4.

struct SubP {
    const float* x; const float* gamma; const float* beta;
    const float* W1; const float* b1; const float* W2; const float* b2;
    const float* W3; const float* b3;
    float* sum; float* sumsq; float* a; float* b1p; float* hout;
    int F;
};
struct SubP3 { SubP s[3]; };

// ---------------- BatchNorm stats: 64 rows/block, grid (128,3) ----------------
// r5 post-mortem: the old atomicAdd storm (786K device-scope atomics onto 4K addresses,
// WRITE_SIZE 16.8MB, 53us) serialized at the coherence point. Now: contention-FREE
// partials: block blk writes sum -> p.sum[blk*2048 + f], sumsq -> +1024 (coalesced
// f32x4 stores, zero atomics). prep3 reduces the 128 partials.
__global__ void __launch_bounds__(256) stats3_kernel(SubP3 P) {
    const SubP p = P.s[blockIdx.z];
    int t = threadIdx.x;
    int blk = blockIdx.x;
    int row0 = blk * 64;
    if (p.F == 1024) {
        f32x4 s = {0.f, 0.f, 0.f, 0.f}, s2 = {0.f, 0.f, 0.f, 0.f};
        const float* xp = p.x + (size_t)row0 * 1024 + t * 4;
        #pragma unroll 8
        for (int r = 0; r < 64; r++) {
            f32x4 v = *(const f32x4*)(xp + (size_t)r * 1024);
            s += v; s2 += v * v;
        }
        int f = t * 4;
        *(f32x4*)&p.sum[(size_t)blk * 2048 + f]   = s;
        *(f32x4*)&p.sumsq[(size_t)blk * 2048 + f] = s2;   // sumsq = sum+1024
    } else {
        __shared__ float ls[16], ls2[16];
        if (t < 16) { ls[t] = 0.f; ls2[t] = 0.f; }
        __syncthreads();
        int F = p.F;
        for (int idx = t; idx < 64 * F; idx += 256) {
            float v = p.x[(size_t)row0 * F + idx];
            int f = idx % 10;            // row0*F ≡ 0 (mod F)
            atomicAdd(&ls[f], v);        // LDS-scope only (cheap)
            atomicAdd(&ls2[f], v * v);
        }
        __syncthreads();
        if (t < F) {
            p.sum[(size_t)blk * 2048 + t]   = ls[t];
            p.sumsq[(size_t)blk * 2048 + t] = ls2[t];
        }
    }
}

// ---------------- finalize stats: reduce 128 partials; a[f]; c@W1 fold -> atomic b1p ----
__global__ void prep3_kernel(SubP3 P) {
    const SubP p = P.s[blockIdx.y];
    int f0 = blockIdx.x * 32;
    if (f0 >= p.F) return;
    int t = threadIdx.x;
    __shared__ float c_sh[32];
    __shared__ float red[8][33];
    __shared__ float rs[8][33], rs2[8][33];
    int fc = p.F - f0; if (fc > 32) fc = 32;
    int fi = t & 31, g = t >> 5;
    {   // reduce the 128 per-block partials (8 groups x 16 blocks each)
        float s = 0.f, s2 = 0.f;
        if (fi < fc) {
            for (int blk = g; blk < 128; blk += 8) {
                s  += p.sum[(size_t)blk * 2048 + f0 + fi];
                s2 += p.sumsq[(size_t)blk * 2048 + f0 + fi];
            }
        }
        rs[g][fi] = s; rs2[g][fi] = s2;
    }
    __syncthreads();
    if (t < 32) {
        float c = 0.f;
        if (t < fc) {
            float sm = 0.f, sq = 0.f;
            #pragma unroll
            for (int gg = 0; gg < 8; gg++) { sm += rs[gg][t]; sq += rs2[gg][t]; }
            int f = f0 + t;
            float mu  = sm * (1.f / 8192.f);
            float var = sq * (1.f / 8192.f) - mu * mu;
            float a = p.gamma[f] * rsqrtf(var + 1e-5f);
            p.a[f] = a;
            c = p.beta[f] - mu * a;
        }
        c_sh[t] = c;
    }
    __syncthreads();
    int h = t & 31; g = t >> 5;
    float s = 0.f;
    for (int fi2 = g; fi2 < fc; fi2 += 8)
        s += c_sh[fi2] * p.W1[(size_t)(f0 + fi2) * 32 + h];
    red[g][h] = s;
    __syncthreads();
    if (t < 32) {
        float tot = 0.f;
        #pragma unroll
        for (int gg = 0; gg < 8; gg++) tot += red[gg][t];
        atomicAdd(&p.b1p[t], tot);
    }
}

// ---------------- Subnet MLP: 32 rows/block, 4h x 8r tile, k-split 8 ----------------
__global__ void __launch_bounds__(256) subnet3_kernel(SubP3 P) {
    const SubP p = P.s[blockIdx.y];
    const int F = p.F;
    __shared__ float smem[8832];
    float* Red = smem;            // 3 x [32][36] = 3456
    float* H1  = smem + 3456;     // [32][36] -> 4608
    float* W23 = smem + 4608;     // [32][33] -> 5664
    float* H2  = smem;            // [32][36]

    int t = threadIdx.x;
    int row0 = blockIdx.x * 32;
    int kg = t >> 6;
    int lane = t & 63;
    int hg = lane & 7, h0 = hg * 4;
    int rg = (lane >> 3) & 3;
    int ks = lane >> 5;

    float acc[4][8] = {};         // [hi][ri], rows rg + 4*ri

    if (F == 1024) {
        float* Xt = smem;             // [32][132] = 4224
        float* Wt = smem + 4224;      // [128][36] = 4608 -> 8832
        int xr = t >> 3, xc = (t & 7) * 16;
        int wk = t >> 1, wh = (t & 1) * 16;
        const float* xbase = p.x + (size_t)row0 * 1024;
        f32x4 xp[4], wp[4]; float av;
        #pragma unroll
        for (int i = 0; i < 4; i++) xp[i] = *(const f32x4*)&xbase[(size_t)xr * 1024 + xc + i * 4];
        #pragma unroll
        for (int i = 0; i < 4; i++) wp[i] = *(const f32x4*)&p.W1[(size_t)wk * 32 + wh + i * 4];
        av = p.a[wk];
        int kb = (kg * 2 + ks) * 16;
        for (int c = 0; c < 8; c++) {
            __syncthreads();          // prev chunk's reads done
            #pragma unroll
            for (int i = 0; i < 4; i++) *(f32x4*)&Xt[xr * 132 + xc + i * 4] = xp[i];
            #pragma unroll
            for (int i = 0; i < 4; i++) *(f32x4*)&Wt[wk * 36 + wh + i * 4] = wp[i] * av;
            if (c < 7) {
                int k0 = (c + 1) * 128;
                #pragma unroll
                for (int i = 0; i < 4; i++) xp[i] = *(const f32x4*)&xbase[(size_t)xr * 1024 + k0 + xc + i * 4];
                #pragma unroll
                for (int i = 0; i < 4; i++) wp[i] = *(const f32x4*)&p.W1[(size_t)(k0 + wk) * 32 + wh + i * 4];
                av = p.a[k0 + wk];
            }
            __syncthreads();          // tiles ready
            #pragma unroll
            for (int s = 0; s < 4; s++) {
                int kk = kb + s * 4;
                f32x4 wv[4], xv[8];
                #pragma unroll
                for (int j = 0; j < 4; j++)  wv[j]  = *(const f32x4*)&Wt[(kk + j) * 36 + h0];
                #pragma unroll
                for (int ri = 0; ri < 8; ri++) xv[ri] = *(const f32x4*)&Xt[(rg + 4 * ri) * 132 + kk];
                #pragma unroll
                for (int j = 0; j < 4; j++)
                    #pragma unroll
                    for (int hi = 0; hi < 4; hi++) {
                        float w = wv[j][hi];
                        #pragma unroll
                        for (int ri = 0; ri < 8; ri++)
                            acc[hi][ri] = fmaf(w, xv[ri][j], acc[hi][ri]);
                    }
            }
        }
    } else {
        float* Xt = smem;             // [32][68]
        float* Wt = smem + 2176;      // [64][36]
        int kbase = (kg * 2 + ks) * 8;
        for (int k0 = 0; k0 < F; k0 += 64) {
            int kc = F - k0; if (kc > 64) kc = 64;
            int kcp = (kc + 3) & ~3;
            __syncthreads();
            for (int idx = t; idx < 32 * kcp; idx += 256) {
                int r = idx / kcp, kk = idx - r * kcp;
                Xt[r * 68 + kk] = (kk < kc) ? p.x[(size_t)(row0 + r) * F + k0 + kk] : 0.f;
            }
            for (int idx = t; idx < kcp * 32; idx += 256) {
                int kk = idx >> 5, hh = idx & 31;
                Wt[kk * 36 + hh] = (kk < kc) ? p.a[k0 + kk] * p.W1[(size_t)(k0 + kk) * 32 + hh] : 0.f;
            }
            __syncthreads();
            #pragma unroll
            for (int s = 0; s < 2; s++) {
                int kk = kbase + s * 4;
                if (kk < kcp) {
                    f32x4 wv[4], xv[8];
                    #pragma unroll
                    for (int j = 0; j < 4; j++)  wv[j]  = *(const f32x4*)&Wt[(kk + j) * 36 + h0];
                    #pragma unroll
                    for (int ri = 0; ri < 8; ri++) xv[ri] = *(const f32x4*)&Xt[(rg + 4 * ri) * 68 + kk];
                    #pragma unroll
                    for (int j = 0; j < 4; j++)
                        #pragma unroll
                        for (int hi = 0; hi < 4; hi++) {
                            float w = wv[j][hi];
                            #pragma unroll
                            for (int ri = 0; ri < 8; ri++)
                                acc[hi][ri] = fmaf(w, xv[ri][j], acc[hi][ri]);
                        }
                }
            }
        }
    }
    // merge the two lane-half k-slices in-register
    #pragma unroll
    for (int hi = 0; hi < 4; hi++)
        #pragma unroll
        for (int ri = 0; ri < 8; ri++)
            acc[hi][ri] += __shfl_xor(acc[hi][ri], 32);
    __syncthreads();                              // S1: Xt/Wt dead
    if (kg > 0 && ks == 0) {
        #pragma unroll
        for (int ri = 0; ri < 8; ri++) {
            int r = rg + 4 * ri;
            f32x4 v = {acc[0][ri], acc[1][ri], acc[2][ri], acc[3][ri]};
            *(f32x4*)&Red[(kg - 1) * 1152 + r * 36 + h0] = v;
        }
    }
    for (int idx = t; idx < 1024; idx += 256) W23[(idx >> 5) * 33 + (idx & 31)] = p.W2[idx];
    __syncthreads();                              // S2: Red + W2 ready
    if (kg == 0 && ks == 0) {
        f32x4 b;
        #pragma unroll
        for (int hi = 0; hi < 4; hi++) b[hi] = p.b1[h0 + hi] + p.b1p[h0 + hi];
        #pragma unroll
        for (int ri = 0; ri < 8; ri++) {
            int r = rg + 4 * ri;
            f32x4 v = {acc[0][ri], acc[1][ri], acc[2][ri], acc[3][ri]};
            #pragma unroll
            for (int pp = 0; pp < 3; pp++)
                v += *(const f32x4*)&Red[pp * 1152 + r * 36 + h0];
            v += b;
            #pragma unroll
            for (int hi = 0; hi < 4; hi++)
                H1[r * 36 + h0 + hi] = fmaxf(v[hi], 0.f);
        }
    }
    __syncthreads();                              // S3: H1 ready
    int h = t & 31, rq = t >> 5;                  // 8 groups x 4 rows
    {
        float a2[4] = {};
        for (int q = 0; q < 32; q++) {
            float w = W23[q * 33 + h];
            #pragma unroll
            for (int i = 0; i < 4; i++) a2[i] += H1[(rq * 4 + i) * 36 + q] * w;
        }
        float bv = p.b2[h];
        #pragma unroll
        for (int i = 0; i < 4; i++) H2[(rq * 4 + i) * 36 + h] = fmaxf(a2[i] + bv, 0.f);
    }
    __syncthreads();                              // S4
    for (int idx = t; idx < 1024; idx += 256) W23[(idx >> 5) * 33 + (idx & 31)] = p.W3[idx];
    __syncthreads();                              // S5
    {
        float a3[4] = {};
        for (int q = 0; q < 32; q++) {
            float w = W23[q * 33 + h];
            #pragma unroll
            for (int i = 0; i < 4; i++) a3[i] += H2[(rq * 4 + i) * 36 + q] * w;
        }
        float bv = p.b3[h];
        #pragma unroll
        for (int i = 0; i < 4; i++)
            p.hout[(size_t)(row0 + rq * 4 + i) * 32 + h] = fmaxf(a3[i] + bv, 0.f);
    }
}

// ---------------- p1/W2t build in FRAGMENT-PACKED layout, one launch ----------------
__global__ void build_both(const float* __restrict__ mk_h, const float* __restrict__ us_h,
                           bf16* __restrict__ p1,
                           const float* __restrict__ Wf1, bf16* __restrict__ W2t) {
    int blk = blockIdx.x;
    int t = threadIdx.x;
    if (blk < NB) {
        int b = blk;
        __shared__ float mk1[33], us1[33];
        if (t == 0) { mk1[0] = 1.f; us1[0] = 1.f; }
        if (t < 32) mk1[t + 1] = mk_h[(size_t)b * 32 + t];
        else if (t < 64) us1[t - 31] = us_h[(size_t)b * 32 + (t - 32)];
        __syncthreads();
        if (t < 144) {                         // 144*8 = 1152 = KP
            int base = t * 8;
            s16x8 v;
            #pragma unroll
            for (int e = 0; e < 8; e++) {
                int idx = base + e;
                float val = 0.f;
                if (idx < 1089) {
                    int k = idx / 33, i = idx - k * 33;
                    val = mk1[k] * us1[i];
                }
                __hip_bfloat16 hb = __float2bfloat16(val);
                v[e] = *(short*)&hb;
            }
            int m16 = b >> 4, fr = b & 15;
            size_t fo = ((size_t)(t >> 2) * 512 + m16) * 64 + (t & 3) * 16 + fr;
            *(s16x8*)(p1 + fo * 8) = v;
        }
    } else {
        int kj = blk - NB;
        int k = kj / 33, j = kj - k * 33;
        __shared__ float tile[1089];
        const float* src = Wf1 + (size_t)k * 35937 + (size_t)j * 1089;  // [i][o] contiguous
        for (int idx = t; idx < 1089; idx += 192) tile[idx] = src[idx];
        __syncthreads();
        for (int idx = t; idx < 1089; idx += 192) {
            int o = idx / 33, i = idx - o * 33;
            int R = j * 33 + o;          // B row (= output column n)
            int C = k * 33 + i;          // B col (= K index)
            int fn = R >> 4, fr = R & 15;
            int kss = C >> 5, q = (C >> 3) & 3, e = C & 7;
            size_t fo = ((size_t)kss * 72 + fn) * 64 + q * 16 + fr;
            W2t[fo * 8 + e] = __float2bfloat16(tile[i * 33 + o]);
        }
        if (k == 0) {
            // zero the K-pad (C = 1089..1151) for this j's 33 B rows
            bf16 z = __float2bfloat16(0.f);
            for (int idx = t; idx < 33 * 63; idx += 192) {
                int o = idx / 63, C = 1089 + idx - o * 63;
                int R = j * 33 + o;
                int fn = R >> 4, fr = R & 15;
                int kss = C >> 5, q = (C >> 3) & 3, e = C & 7;
                size_t fo = ((size_t)kss * 72 + fn) * 64 + q * 16 + fr;
                W2t[fo * 8 + e] = z;
            }
        }
    }
}

// ---------------- FUSED GEMM + epilogue: out = sigmoid(relu(...) @ Wf2 + bf2) ----------
// Block owns rows [bid*32, +32) x FULL N=1152 -> the j-contraction never crosses blocks,
// so S (18.9MB HBM write + 18.9MB read + a dispatch) is eliminated entirely.
// 4 waves; wave wn covers cols [wn*288,+288): acc 2x18 f32x4 (144 VGPR); B loaded in
// 9-frag halves to cap regs (~210); operands = round-5-verified packed fragments.
// Per block: A 74KB (HBM once) + full W2t 2.65MB from L2 (256 blks -> ~700MB L2 ~20us).
// Epilogue: acc -> LDS Sl[32][1156] bf16 (stride 1156: 4-row write groups hit banks
// +0/8/16/24), barrier, h[row][o] = relu(bf1[o]+Sum_j cd1[row][j]*Sl[row][j*33+o]),
// then 33x5 + sigmoid -> out. hsh overlays Sl (barrier-separated).
__global__ void __launch_bounds__(256, 2) gemm_fused(const bf16* __restrict__ pA,
                                                     const bf16* __restrict__ pB,
                                                     const float* __restrict__ cd_h,
                                                     const float* __restrict__ bf1,
                                                     const float* __restrict__ Wf2,
                                                     const float* __restrict__ bf2,
                                                     float* __restrict__ out) {
    __shared__ __align__(16) unsigned short Sl[32 * 1156];   // 73984 B
    __shared__ float cdl[32][33];                            // 4224 B
    int t = threadIdx.x;
    int bid = blockIdx.x;
    int m0 = bid * 32;
    int wave = t >> 6, lane = t & 63;
    int wn = wave;                      // wave covers cols [wn*288, +288)

    // stage cd1 rows (with leading 1) for this block
    for (int u = t; u < 32 * 33; u += 256) {
        int row = u / 33, j = u - row * 33;
        cdl[row][j] = (j == 0) ? 1.f : cd_h[(size_t)(m0 + row) * 32 + (j - 1)];
    }

    const s16x8* Ap = (const s16x8*)pA;
    const s16x8* Bp = (const s16x8*)pB;

    f32x4 acc[2][18] = {};

    for (int ks = 0; ks < NK; ks++) {
        size_t ab = ((size_t)ks * 512 + bid * 2) * 64 + lane;
        s16x8 af0 = Ap[ab];
        s16x8 af1 = Ap[ab + 64];
        #pragma unroll
        for (int hh = 0; hh < 2; hh++) {
            size_t bb = ((size_t)ks * 72 + wn * 18 + hh * 9) * 64 + lane;
            s16x8 bf[9];
            #pragma unroll
            for (int nt = 0; nt < 9; nt++) bf[nt] = Bp[bb + nt * 64];
            #pragma unroll
            for (int nt = 0; nt < 9; nt++) {
                int n2 = hh * 9 + nt;
                acc[0][n2] = __builtin_amdgcn_mfma_f32_16x16x32_bf16(af0, bf[nt], acc[0][n2], 0, 0, 0);
                acc[1][n2] = __builtin_amdgcn_mfma_f32_16x16x32_bf16(af1, bf[nt], acc[1][n2], 0, 0, 0);
            }
        }
    }

    // acc -> LDS (bf16). C-layout: col = lane&15, row = (lane>>4)*4 + r (r5-verified).
    int col = lane & 15, rowg = (lane >> 4) * 4;
    #pragma unroll
    for (int mt = 0; mt < 2; mt++)
        #pragma unroll
        for (int n2 = 0; n2 < 18; n2++)
            #pragma unroll
            for (int r = 0; r < 4; r++) {
                int lrow = mt * 16 + rowg + r;
                int lcol = wn * 288 + n2 * 16 + col;
                __hip_bfloat16 hb = __float2bfloat16(acc[mt][n2][r]);
                Sl[lrow * 1156 + lcol] = *(unsigned short*)&hb;
            }
    __syncthreads();                    // Sl + cdl ready

    // j-contraction: h[row][o] = relu(bf1[o] + Sum_j cdl[row][j] * Sl[row][j*33+o])
    float hreg[5];
    int nh = 0;
    for (int u = t; u < 32 * 33; u += 256, nh++) {
        int row = u / 33, o = u - row * 33;
        float a = bf1[o];
        #pragma unroll 3
        for (int j = 0; j < 33; j++) {
            unsigned short sv = Sl[row * 1156 + j * 33 + o];
            a += cdl[row][j] * __bfloat162float(*(bf16*)&sv);
        }
        hreg[nh] = fmaxf(a, 0.f);
    }
    __syncthreads();                    // all Sl reads done; safe to overlay
    float* hsh = (float*)&Sl[0];        // [32][33] reuse
    nh = 0;
    for (int u = t; u < 32 * 33; u += 256, nh++) hsh[u] = hreg[nh];
    __syncthreads();
    if (t < 160) {
        int row = t / 5, o2 = t - row * 5;
        float v = bf2[o2];
        for (int q = 0; q < 33; q++) v += hsh[row * 33 + q] * Wf2[q * 5 + o2];
        out[(size_t)(m0 + row) * 5 + o2] = 1.f / (1.f + expf(-v));
    }
}

extern "C" void kernel_launch(void* const* d_in, const int* in_sizes, int n_in,
                              void* d_out, int out_size, void* d_ws, size_t ws_size,
                              hipStream_t stream) {
    const float* US_x     = (const float*)d_in[0];
    const float* CDFI_x   = (const float*)d_in[1];
    const float* marker_x = (const float*)d_in[2];
    const float* Wf1      = (const float*)d_in[27];
    const float* bf1      = (const float*)d_in[28];
    const float* Wf2      = (const float*)d_in[29];
    const float* bf2      = (const float*)d_in[30];
    float* out = (float*)d_out;

    char* ws = (char*)d_ws;
    size_t off = 0;
    auto alloc = [&](size_t bytes) -> void* {
        void* p = ws + off;
        off = (off + bytes + 255) & ~(size_t)255;
        return p;
    };

    float* b1p_buf  = (float*)alloc(3 * 128 * sizeof(float));          // zeroed
    float* pstat    = (float*)alloc(3 * 128 * 2048 * sizeof(float));   // partials, no init
    float* a_buf[3], *h_buf[3];
    for (int i = 0; i < 3; i++) {
        a_buf[i] = (float*)alloc(1024 * 4);
        h_buf[i] = (float*)alloc((size_t)NB * 32 * 4);
    }
    bf16*  p1   = (bf16*)alloc((size_t)NB * KP * 2);   // fragment-packed A
    bf16*  W2t  = (bf16*)alloc((size_t)NP * KP * 2);   // fragment-packed B

    SubP3 P;
    const float* xs[3] = {US_x, CDFI_x, marker_x};
    int Fs[3] = {1024, 1024, 10};
    for (int i = 0; i < 3; i++) {
        int base = 3 + i * 8;
        P.s[i].x     = xs[i];
        P.s[i].gamma = (const float*)d_in[base + 0];
        P.s[i].beta  = (const float*)d_in[base + 1];
        P.s[i].W1    = (const float*)d_in[base + 2];
        P.s[i].b1    = (const float*)d_in[base + 3];
        P.s[i].W2    = (const float*)d_in[base + 4];
        P.s[i].b2    = (const float*)d_in[base + 5];
        P.s[i].W3    = (const float*)d_in[base + 6];
        P.s[i].b3    = (const float*)d_in[base + 7];
        P.s[i].sum   = pstat + (size_t)i * 128 * 2048;         // partial sums
        P.s[i].sumsq = pstat + (size_t)i * 128 * 2048 + 1024;  // partial sumsq
        P.s[i].b1p   = b1p_buf + i * 128;
        P.s[i].a     = a_buf[i];
        P.s[i].hout  = h_buf[i];
        P.s[i].F     = Fs[i];
    }

    float* us_h = h_buf[0];
    float* cd_h = h_buf[1];
    float* mk_h = h_buf[2];

    hipMemsetAsync(b1p_buf, 0, 3 * 128 * sizeof(float), stream);

    stats3_kernel<<<dim3(128, 1, 3), 256, 0, stream>>>(P);
    prep3_kernel<<<dim3(32, 3), 256, 0, stream>>>(P);
    subnet3_kernel<<<dim3(256, 3), 256, 0, stream>>>(P);

    build_both<<<NB + 1089, 192, 0, stream>>>(mk_h, us_h, p1, Wf1, W2t);

    gemm_fused<<<NB / 32, 256, 0, stream>>>(p1, W2t, cd_h, bf1, Wf2, bf2, out);
}

// Round 7
// 256.984 us; speedup vs baseline: 1.2521x; 1.2521x over previous
//
#include <hip/hip_runtime.h>
#include <hip/hip_bf16.h>
#include <math.h>

typedef __hip_bfloat16 bf16;
typedef __attribute__((ext_vector_type(4))) float f32x4;
typedef __attribute__((ext_vector_type(8))) short s16x8;

#define NB 8192
#define KP 1152   // padded K: 1089 -> 36*32
#define NP 1152   // padded N: 1089 -> 9*128
#define NK 36     // KP/32

struct SubP {
    const float* x; const float* gamma; const float* beta;
    const float* W1; const float* b1; const float* W2; const float* b2;
    const float* W3; const float* b3;
    float* sum; float* sumsq; float* a; float* b1p; float* hout;
    int F;
};
struct SubP3 { SubP s[3]; };

// ---------------- BatchNorm stats: 64 rows/block, grid (128,3) ----------------
// Contention-free partials (R6-verified): block blk writes sum -> p.sum[blk*2048+f],
// sumsq -> +1024 (coalesced f32x4 stores, zero device atomics). The old atomic
// version serialized 262K-786K device atomics onto 4K addresses (53us measured, r4).
__global__ void __launch_bounds__(256) stats3_kernel(SubP3 P) {
    const SubP p = P.s[blockIdx.z];
    int t = threadIdx.x;
    int blk = blockIdx.x;
    int row0 = blk * 64;
    if (p.F == 1024) {
        f32x4 s = {0.f, 0.f, 0.f, 0.f}, s2 = {0.f, 0.f, 0.f, 0.f};
        const float* xp = p.x + (size_t)row0 * 1024 + t * 4;
        #pragma unroll 8
        for (int r = 0; r < 64; r++) {
            f32x4 v = *(const f32x4*)(xp + (size_t)r * 1024);
            s += v; s2 += v * v;
        }
        int f = t * 4;
        *(f32x4*)&p.sum[(size_t)blk * 2048 + f]   = s;
        *(f32x4*)&p.sumsq[(size_t)blk * 2048 + f] = s2;
    } else {
        __shared__ float ls[16], ls2[16];
        if (t < 16) { ls[t] = 0.f; ls2[t] = 0.f; }
        __syncthreads();
        int F = p.F;
        for (int idx = t; idx < 64 * F; idx += 256) {
            float v = p.x[(size_t)row0 * F + idx];
            int f = idx % 10;            // row0*F ≡ 0 (mod F)
            atomicAdd(&ls[f], v);        // LDS-scope only
            atomicAdd(&ls2[f], v * v);
        }
        __syncthreads();
        if (t < F) {
            p.sum[(size_t)blk * 2048 + t]   = ls[t];
            p.sumsq[(size_t)blk * 2048 + t] = ls2[t];
        }
    }
}

// ---------------- finalize stats: reduce 128 partials; a[f]; c@W1 fold -> atomic b1p ----
__global__ void prep3_kernel(SubP3 P) {
    const SubP p = P.s[blockIdx.y];
    int f0 = blockIdx.x * 32;
    if (f0 >= p.F) return;
    int t = threadIdx.x;
    __shared__ float c_sh[32];
    __shared__ float red[8][33];
    __shared__ float rs[8][33], rs2[8][33];
    int fc = p.F - f0; if (fc > 32) fc = 32;
    int fi = t & 31, g = t >> 5;
    {   // reduce the 128 per-block partials (8 groups x 16 blocks each)
        float s = 0.f, s2 = 0.f;
        if (fi < fc) {
            for (int blk = g; blk < 128; blk += 8) {
                s  += p.sum[(size_t)blk * 2048 + f0 + fi];
                s2 += p.sumsq[(size_t)blk * 2048 + f0 + fi];
            }
        }
        rs[g][fi] = s; rs2[g][fi] = s2;
    }
    __syncthreads();
    if (t < 32) {
        float c = 0.f;
        if (t < fc) {
            float sm = 0.f, sq = 0.f;
            #pragma unroll
            for (int gg = 0; gg < 8; gg++) { sm += rs[gg][t]; sq += rs2[gg][t]; }
            int f = f0 + t;
            float mu  = sm * (1.f / 8192.f);
            float var = sq * (1.f / 8192.f) - mu * mu;
            float a = p.gamma[f] * rsqrtf(var + 1e-5f);
            p.a[f] = a;
            c = p.beta[f] - mu * a;
        }
        c_sh[t] = c;
    }
    __syncthreads();
    int h = t & 31; g = t >> 5;
    float s = 0.f;
    for (int fi2 = g; fi2 < fc; fi2 += 8)
        s += c_sh[fi2] * p.W1[(size_t)(f0 + fi2) * 32 + h];
    red[g][h] = s;
    __syncthreads();
    if (t < 32) {
        float tot = 0.f;
        #pragma unroll
        for (int gg = 0; gg < 8; gg++) tot += red[gg][t];
        atomicAdd(&p.b1p[t], tot);
    }
}

// ---------------- Subnet MLP: 32 rows/block, 4h x 8r tile, k-split 8 ----------------
__global__ void __launch_bounds__(256) subnet3_kernel(SubP3 P) {
    const SubP p = P.s[blockIdx.y];
    const int F = p.F;
    __shared__ float smem[8832];
    float* Red = smem;            // 3 x [32][36] = 3456
    float* H1  = smem + 3456;     // [32][36] -> 4608
    float* W23 = smem + 4608;     // [32][33] -> 5664
    float* H2  = smem;            // [32][36]

    int t = threadIdx.x;
    int row0 = blockIdx.x * 32;
    int kg = t >> 6;
    int lane = t & 63;
    int hg = lane & 7, h0 = hg * 4;
    int rg = (lane >> 3) & 3;
    int ks = lane >> 5;

    float acc[4][8] = {};         // [hi][ri], rows rg + 4*ri

    if (F == 1024) {
        float* Xt = smem;             // [32][132] = 4224
        float* Wt = smem + 4224;      // [128][36] = 4608 -> 8832
        int xr = t >> 3, xc = (t & 7) * 16;
        int wk = t >> 1, wh = (t & 1) * 16;
        const float* xbase = p.x + (size_t)row0 * 1024;
        f32x4 xp[4], wp[4]; float av;
        #pragma unroll
        for (int i = 0; i < 4; i++) xp[i] = *(const f32x4*)&xbase[(size_t)xr * 1024 + xc + i * 4];
        #pragma unroll
        for (int i = 0; i < 4; i++) wp[i] = *(const f32x4*)&p.W1[(size_t)wk * 32 + wh + i * 4];
        av = p.a[wk];
        int kb = (kg * 2 + ks) * 16;
        for (int c = 0; c < 8; c++) {
            __syncthreads();          // prev chunk's reads done
            #pragma unroll
            for (int i = 0; i < 4; i++) *(f32x4*)&Xt[xr * 132 + xc + i * 4] = xp[i];
            #pragma unroll
            for (int i = 0; i < 4; i++) *(f32x4*)&Wt[wk * 36 + wh + i * 4] = wp[i] * av;
            if (c < 7) {
                int k0 = (c + 1) * 128;
                #pragma unroll
                for (int i = 0; i < 4; i++) xp[i] = *(const f32x4*)&xbase[(size_t)xr * 1024 + k0 + xc + i * 4];
                #pragma unroll
                for (int i = 0; i < 4; i++) wp[i] = *(const f32x4*)&p.W1[(size_t)(k0 + wk) * 32 + wh + i * 4];
                av = p.a[k0 + wk];
            }
            __syncthreads();          // tiles ready
            #pragma unroll
            for (int s = 0; s < 4; s++) {
                int kk = kb + s * 4;
                f32x4 wv[4], xv[8];
                #pragma unroll
                for (int j = 0; j < 4; j++)  wv[j]  = *(const f32x4*)&Wt[(kk + j) * 36 + h0];
                #pragma unroll
                for (int ri = 0; ri < 8; ri++) xv[ri] = *(const f32x4*)&Xt[(rg + 4 * ri) * 132 + kk];
                #pragma unroll
                for (int j = 0; j < 4; j++)
                    #pragma unroll
                    for (int hi = 0; hi < 4; hi++) {
                        float w = wv[j][hi];
                        #pragma unroll
                        for (int ri = 0; ri < 8; ri++)
                            acc[hi][ri] = fmaf(w, xv[ri][j], acc[hi][ri]);
                    }
            }
        }
    } else {
        float* Xt = smem;             // [32][68]
        float* Wt = smem + 2176;      // [64][36]
        int kbase = (kg * 2 + ks) * 8;
        for (int k0 = 0; k0 < F; k0 += 64) {
            int kc = F - k0; if (kc > 64) kc = 64;
            int kcp = (kc + 3) & ~3;
            __syncthreads();
            for (int idx = t; idx < 32 * kcp; idx += 256) {
                int r = idx / kcp, kk = idx - r * kcp;
                Xt[r * 68 + kk] = (kk < kc) ? p.x[(size_t)(row0 + r) * F + k0 + kk] : 0.f;
            }
            for (int idx = t; idx < kcp * 32; idx += 256) {
                int kk = idx >> 5, hh = idx & 31;
                Wt[kk * 36 + hh] = (kk < kc) ? p.a[k0 + kk] * p.W1[(size_t)(k0 + kk) * 32 + hh] : 0.f;
            }
            __syncthreads();
            #pragma unroll
            for (int s = 0; s < 2; s++) {
                int kk = kbase + s * 4;
                if (kk < kcp) {
                    f32x4 wv[4], xv[8];
                    #pragma unroll
                    for (int j = 0; j < 4; j++)  wv[j]  = *(const f32x4*)&Wt[(kk + j) * 36 + h0];
                    #pragma unroll
                    for (int ri = 0; ri < 8; ri++) xv[ri] = *(const f32x4*)&Xt[(rg + 4 * ri) * 68 + kk];
                    #pragma unroll
                    for (int j = 0; j < 4; j++)
                        #pragma unroll
                        for (int hi = 0; hi < 4; hi++) {
                            float w = wv[j][hi];
                            #pragma unroll
                            for (int ri = 0; ri < 8; ri++)
                                acc[hi][ri] = fmaf(w, xv[ri][j], acc[hi][ri]);
                        }
                }
            }
        }
    }
    // merge the two lane-half k-slices in-register
    #pragma unroll
    for (int hi = 0; hi < 4; hi++)
        #pragma unroll
        for (int ri = 0; ri < 8; ri++)
            acc[hi][ri] += __shfl_xor(acc[hi][ri], 32);
    __syncthreads();                              // S1: Xt/Wt dead
    if (kg > 0 && ks == 0) {
        #pragma unroll
        for (int ri = 0; ri < 8; ri++) {
            int r = rg + 4 * ri;
            f32x4 v = {acc[0][ri], acc[1][ri], acc[2][ri], acc[3][ri]};
            *(f32x4*)&Red[(kg - 1) * 1152 + r * 36 + h0] = v;
        }
    }
    for (int idx = t; idx < 1024; idx += 256) W23[(idx >> 5) * 33 + (idx & 31)] = p.W2[idx];
    __syncthreads();                              // S2: Red + W2 ready
    if (kg == 0 && ks == 0) {
        f32x4 b;
        #pragma unroll
        for (int hi = 0; hi < 4; hi++) b[hi] = p.b1[h0 + hi] + p.b1p[h0 + hi];
        #pragma unroll
        for (int ri = 0; ri < 8; ri++) {
            int r = rg + 4 * ri;
            f32x4 v = {acc[0][ri], acc[1][ri], acc[2][ri], acc[3][ri]};
            #pragma unroll
            for (int pp = 0; pp < 3; pp++)
                v += *(const f32x4*)&Red[pp * 1152 + r * 36 + h0];
            v += b;
            #pragma unroll
            for (int hi = 0; hi < 4; hi++)
                H1[r * 36 + h0 + hi] = fmaxf(v[hi], 0.f);
        }
    }
    __syncthreads();                              // S3: H1 ready
    int h = t & 31, rq = t >> 5;                  // 8 groups x 4 rows
    {
        float a2[4] = {};
        for (int q = 0; q < 32; q++) {
            float w = W23[q * 33 + h];
            #pragma unroll
            for (int i = 0; i < 4; i++) a2[i] += H1[(rq * 4 + i) * 36 + q] * w;
        }
        float bv = p.b2[h];
        #pragma unroll
        for (int i = 0; i < 4; i++) H2[(rq * 4 + i) * 36 + h] = fmaxf(a2[i] + bv, 0.f);
    }
    __syncthreads();                              // S4
    for (int idx = t; idx < 1024; idx += 256) W23[(idx >> 5) * 33 + (idx & 31)] = p.W3[idx];
    __syncthreads();                              // S5
    {
        float a3[4] = {};
        for (int q = 0; q < 32; q++) {
            float w = W23[q * 33 + h];
            #pragma unroll
            for (int i = 0; i < 4; i++) a3[i] += H2[(rq * 4 + i) * 36 + q] * w;
        }
        float bv = p.b3[h];
        #pragma unroll
        for (int i = 0; i < 4; i++)
            p.hout[(size_t)(row0 + rq * 4 + i) * 32 + h] = fmaxf(a3[i] + bv, 0.f);
    }
}

// ---------------- p1 build + W2t transpose (incl. K-pad zeroing), one launch ----------------
__global__ void build_both(const float* __restrict__ mk_h, const float* __restrict__ us_h,
                           bf16* __restrict__ p1,
                           const float* __restrict__ Wf1, bf16* __restrict__ W2t) {
    int blk = blockIdx.x;
    int t = threadIdx.x;
    if (blk < NB) {
        int b = blk;
        __shared__ float mk1[33], us1[33];
        if (t == 0) { mk1[0] = 1.f; us1[0] = 1.f; }
        if (t < 32) mk1[t + 1] = mk_h[(size_t)b * 32 + t];
        else if (t < 64) us1[t - 31] = us_h[(size_t)b * 32 + (t - 32)];
        __syncthreads();
        if (t < 144) {                         // 144*8 = 1152 = KP
            int base = t * 8;
            s16x8 v;
            #pragma unroll
            for (int e = 0; e < 8; e++) {
                int idx = base + e;
                float val = 0.f;
                if (idx < 1089) {
                    int k = idx / 33, i = idx - k * 33;
                    val = mk1[k] * us1[i];
                }
                __hip_bfloat16 hb = __float2bfloat16(val);
                v[e] = *(short*)&hb;
            }
            *(s16x8*)(p1 + (size_t)b * KP + base) = v;
        }
    } else {
        int kj = blk - NB;
        int k = kj / 33, j = kj - k * 33;
        __shared__ float tile[1089];
        const float* src = Wf1 + (size_t)k * 35937 + (size_t)j * 1089;  // [i][o] contiguous
        for (int idx = t; idx < 1089; idx += 192) tile[idx] = src[idx];
        __syncthreads();
        for (int idx = t; idx < 1089; idx += 192) {
            int o = idx / 33, i = idx - o * 33;
            W2t[(size_t)(j * 33 + o) * KP + k * 33 + i] = __float2bfloat16(tile[i * 33 + o]);
        }
        if (k == 0) {
            // zero the K-pad (kk 1089..1151) for this j's 33 n-rows
            bf16 z = __float2bfloat16(0.f);
            for (int idx = t; idx < 33 * 63; idx += 192) {
                int o = idx / 63, kkp = 1089 + idx - o * 63;
                W2t[(size_t)(j * 33 + o) * KP + kkp] = z;
            }
        }
    }
}

// ---------------- Main GEMM: S[8192,1152] = p1 @ W2t^T ----------------
// R2 configuration (best measured: 42.6us, conflicts 0). 128x128 tile, BK=32
// double-buffered, one barrier per k-step, stage(t+1) before compute(t).
// Swizzle (rule 21, both-sides): XOR 16B slot with (row>>1)&3 on both the staged
// global source and the frag read. R1-R6 established the time is pinned ~43us
// regardless of micro-structure; keep the known-good variant.
__global__ void __launch_bounds__(256) gemm_kernel(const bf16* __restrict__ A,   // [NB][KP]
                                                   const bf16* __restrict__ Bt,  // [NP][KP]
                                                   bf16* __restrict__ S) {       // [NB][NP]
    __shared__ __align__(16) bf16 As[2][128 * 32];
    __shared__ __align__(16) bf16 Bs[2][128 * 32];
    int t = threadIdx.x;
    int m0 = blockIdx.x * 128;
    int n0 = blockIdx.y * 128;
    int wave = t >> 6, lane = t & 63;
    int wm = (wave & 1) * 64, wn = (wave >> 1) * 64;
    int fr = lane & 15;
    int q  = lane >> 4;                         // global 16B slot of the frag (k = q*8)
    int rsw = (fr >> 1) & 3;                    // read-side XOR term

    int lr = lane >> 2;
    int sslot = (lane & 3) ^ ((lane >> 3) & 3);
    const bf16* Ag = A  + (size_t)(m0 + wave * 32 + lr) * KP + sslot * 8;
    const bf16* Bg = Bt + (size_t)(n0 + wave * 32 + lr) * KP + sslot * 8;

    f32x4 acc[4][4] = {};

    auto stage = [&](int buf, int k0) {
        bf16* Ad = &As[buf][wave * 1024];
        bf16* Bd = &Bs[buf][wave * 1024];
        __builtin_amdgcn_global_load_lds(
            (const __attribute__((address_space(1))) void*)(Ag + k0),
            (__attribute__((address_space(3))) void*)(Ad), 16, 0, 0);
        __builtin_amdgcn_global_load_lds(
            (const __attribute__((address_space(1))) void*)(Ag + k0 + (size_t)16 * KP),
            (__attribute__((address_space(3))) void*)(Ad + 16 * 32), 16, 0, 0);
        __builtin_amdgcn_global_load_lds(
            (const __attribute__((address_space(1))) void*)(Bg + k0),
            (__attribute__((address_space(3))) void*)(Bd), 16, 0, 0);
        __builtin_amdgcn_global_load_lds(
            (const __attribute__((address_space(1))) void*)(Bg + k0 + (size_t)16 * KP),
            (__attribute__((address_space(3))) void*)(Bd + 16 * 32), 16, 0, 0);
    };

    stage(0, 0);
    __syncthreads();                            // buf0 ready
    int cur = 0;
    for (int ks = 0; ks < NK; ks++) {
        if (ks < NK - 1) stage(cur ^ 1, (ks + 1) * 32);   // issue BEFORE compute
        const bf16* Ab = &As[cur][0];
        const bf16* Bb = &Bs[cur][0];
        s16x8 bfr[4];
        #pragma unroll
        for (int nt = 0; nt < 4; nt++) {
            int row = wn + nt * 16 + fr;
            bfr[nt] = *(const s16x8*)(Bb + row * 32 + ((q ^ rsw) * 8));
        }
        #pragma unroll
        for (int mt = 0; mt < 4; mt++) {
            int row = wm + mt * 16 + fr;
            s16x8 af = *(const s16x8*)(Ab + row * 32 + ((q ^ rsw) * 8));
            #pragma unroll
            for (int nt = 0; nt < 4; nt++)
                acc[mt][nt] = __builtin_amdgcn_mfma_f32_16x16x32_bf16(af, bfr[nt], acc[mt][nt], 0, 0, 0);
        }
        __syncthreads();                        // stage(cur^1) drained + reads of cur done
        cur ^= 1;
    }
    int col = lane & 15, rowg = (lane >> 4) * 4;
    #pragma unroll
    for (int mt = 0; mt < 4; mt++)
        #pragma unroll
        for (int nt = 0; nt < 4; nt++)
            #pragma unroll
            for (int r = 0; r < 4; r++) {
                int gr = m0 + wm + mt * 16 + rowg + r;
                int gc = n0 + wn + nt * 16 + col;
                S[(size_t)gr * NP + gc] = __float2bfloat16(acc[mt][nt][r]);
            }
}

// ---------------- Epilogue: stage S rows as bf16 in LDS, contract j, 33x5 + sigmoid ----------
__global__ void __launch_bounds__(256) epilogue_kernel(const bf16* __restrict__ S,
                                const float* __restrict__ cd_h,
                                const float* __restrict__ bf1, const float* __restrict__ Wf2,
                                const float* __restrict__ bf2, float* __restrict__ out) {
    int w = threadIdx.x >> 6;
    int lane = threadIdx.x & 63;
    int b = blockIdx.x * 4 + w;
    __shared__ __align__(16) unsigned short Sl[4][1152];
    __shared__ float cdsh[4][33];
    __shared__ float hsh[4][40];
    // coalesced stage: wave reads its row as 16B chunks (144 chunks of 8 bf16)
    const bf16* Srow = S + (size_t)b * NP;
    #pragma unroll
    for (int pass = 0; pass < 3; pass++) {
        int idx = lane + pass * 64;
        if (idx < 144)
            *(s16x8*)&Sl[w][idx * 8] = *(const s16x8*)(Srow + idx * 8);
    }
    if (lane == 0) cdsh[w][0] = 1.f;
    if (lane < 32) cdsh[w][lane + 1] = cd_h[(size_t)b * 32 + lane];
    __syncthreads();
    if (lane < 33) {
        float acc = bf1[lane];
        #pragma unroll 3
        for (int j = 0; j < 33; j++) {
            unsigned short sv = Sl[w][j * 33 + lane];
            acc += cdsh[w][j] * __bfloat162float(*(bf16*)&sv);
        }
        hsh[w][lane] = fmaxf(acc, 0.f);
    }
    __syncthreads();
    if (lane < 5) {
        float o = bf2[lane];
        for (int q = 0; q < 33; q++) o += hsh[w][q] * Wf2[q * 5 + lane];
        out[(size_t)b * 5 + lane] = 1.f / (1.f + expf(-o));
    }
}

extern "C" void kernel_launch(void* const* d_in, const int* in_sizes, int n_in,
                              void* d_out, int out_size, void* d_ws, size_t ws_size,
                              hipStream_t stream) {
    const float* US_x     = (const float*)d_in[0];
    const float* CDFI_x   = (const float*)d_in[1];
    const float* marker_x = (const float*)d_in[2];
    const float* Wf1      = (const float*)d_in[27];
    const float* bf1      = (const float*)d_in[28];
    const float* Wf2      = (const float*)d_in[29];
    const float* bf2      = (const float*)d_in[30];
    float* out = (float*)d_out;

    char* ws = (char*)d_ws;
    size_t off = 0;
    auto alloc = [&](size_t bytes) -> void* {
        void* p = ws + off;
        off = (off + bytes + 255) & ~(size_t)255;
        return p;
    };

    float* b1p_buf  = (float*)alloc(3 * 128 * sizeof(float));          // zeroed
    float* pstat    = (float*)alloc(3 * 128 * 2048 * sizeof(float));   // partials, no init
    float* a_buf[3], *h_buf[3];
    for (int i = 0; i < 3; i++) {
        a_buf[i] = (float*)alloc(1024 * 4);
        h_buf[i] = (float*)alloc((size_t)NB * 32 * 4);
    }
    bf16*  p1   = (bf16*)alloc((size_t)NB * KP * 2);
    bf16*  W2t  = (bf16*)alloc((size_t)NP * KP * 2);
    bf16*  S    = (bf16*)alloc((size_t)NB * NP * 2);

    SubP3 P;
    const float* xs[3] = {US_x, CDFI_x, marker_x};
    int Fs[3] = {1024, 1024, 10};
    for (int i = 0; i < 3; i++) {
        int base = 3 + i * 8;
        P.s[i].x     = xs[i];
        P.s[i].gamma = (const float*)d_in[base + 0];
        P.s[i].beta  = (const float*)d_in[base + 1];
        P.s[i].W1    = (const float*)d_in[base + 2];
        P.s[i].b1    = (const float*)d_in[base + 3];
        P.s[i].W2    = (const float*)d_in[base + 4];
        P.s[i].b2    = (const float*)d_in[base + 5];
        P.s[i].W3    = (const float*)d_in[base + 6];
        P.s[i].b3    = (const float*)d_in[base + 7];
        P.s[i].sum   = pstat + (size_t)i * 128 * 2048;         // partial sums
        P.s[i].sumsq = pstat + (size_t)i * 128 * 2048 + 1024;  // partial sumsq
        P.s[i].b1p   = b1p_buf + i * 128;
        P.s[i].a     = a_buf[i];
        P.s[i].hout  = h_buf[i];
        P.s[i].F     = Fs[i];
    }

    float* us_h = h_buf[0];
    float* cd_h = h_buf[1];
    float* mk_h = h_buf[2];

    hipMemsetAsync(b1p_buf, 0, 3 * 128 * sizeof(float), stream);

    stats3_kernel<<<dim3(128, 1, 3), 256, 0, stream>>>(P);
    prep3_kernel<<<dim3(32, 3), 256, 0, stream>>>(P);
    subnet3_kernel<<<dim3(256, 3), 256, 0, stream>>>(P);

    build_both<<<NB + 1089, 192, 0, stream>>>(mk_h, us_h, p1, Wf1, W2t);

    gemm_kernel<<<dim3(NB / 128, NP / 128), 256, 0, stream>>>(p1, W2t, S);

    epilogue_kernel<<<NB / 4, 256, 0, stream>>>(S, cd_h, bf1, Wf2, bf2, out);
}

// Round 8
// 254.970 us; speedup vs baseline: 1.2620x; 1.0079x over previous
//
#include <hip/hip_runtime.h>
#include <hip/hip_bf16.h>
#include <math.h>

typedef __hip_bfloat16 bf16;
typedef __attribute__((ext_vector_type(4))) float f32x4;
typedef __attribute__((ext_vector_type(8))) short s16x8;

#define NB 8192
#define KP 1152   // padded K: 1089 -> 36*32
#define NP 1152   // padded N: 1089 -> 9*128
#define NK 36     // KP/32
#define SBLK 256  // stats blocks per subnet (32 rows each)

struct SubP {
    const float* x; const float* gamma; const float* beta;
    const float* W1; const float* b1; const float* W2; const float* b2;
    const float* W3; const float* b3;
    float* sum; float* sumsq; float* a; float* b1p; float* hout;
    int F;
};
struct SubP3 { SubP s[3]; };

// ---------------- BatchNorm stats: 32 rows/block, grid (256,3), contention-free ----------
// Partials (R7-verified): block blk writes sum -> p.sum[blk*2048+f], sumsq -> +1024
// (coalesced f32x4 stores, zero device atomics). 256 blocks/subnet doubles TLP vs R7
// (768 blocks = 3/CU); safe now that there are no atomics (R4's 53us was atomics, not grid).
__global__ void __launch_bounds__(256) stats3_kernel(SubP3 P) {
    const SubP p = P.s[blockIdx.z];
    int t = threadIdx.x;
    int blk = blockIdx.x;
    int row0 = blk * 32;
    if (p.F == 1024) {
        f32x4 s = {0.f, 0.f, 0.f, 0.f}, s2 = {0.f, 0.f, 0.f, 0.f};
        const float* xp = p.x + (size_t)row0 * 1024 + t * 4;
        #pragma unroll 8
        for (int r = 0; r < 32; r++) {
            f32x4 v = *(const f32x4*)(xp + (size_t)r * 1024);
            s += v; s2 += v * v;
        }
        int f = t * 4;
        *(f32x4*)&p.sum[(size_t)blk * 2048 + f]   = s;
        *(f32x4*)&p.sumsq[(size_t)blk * 2048 + f] = s2;
    } else {
        __shared__ float ls[16], ls2[16];
        if (t < 16) { ls[t] = 0.f; ls2[t] = 0.f; }
        __syncthreads();
        int F = p.F;
        for (int idx = t; idx < 32 * F; idx += 256) {
            float v = p.x[(size_t)row0 * F + idx];
            int f = idx % 10;            // row0*F = blk*320 ≡ 0 (mod 10)
            atomicAdd(&ls[f], v);        // LDS-scope only
            atomicAdd(&ls2[f], v * v);
        }
        __syncthreads();
        if (t < F) {
            p.sum[(size_t)blk * 2048 + t]   = ls[t];
            p.sumsq[(size_t)blk * 2048 + t] = ls2[t];
        }
    }
}

// ---------------- finalize stats: reduce 256 partials; a[f]; c@W1 fold -> atomic b1p ----
__global__ void prep3_kernel(SubP3 P) {
    const SubP p = P.s[blockIdx.y];
    int f0 = blockIdx.x * 32;
    if (f0 >= p.F) return;
    int t = threadIdx.x;
    __shared__ float c_sh[32];
    __shared__ float red[8][33];
    __shared__ float rs[8][33], rs2[8][33];
    int fc = p.F - f0; if (fc > 32) fc = 32;
    int fi = t & 31, g = t >> 5;
    {   // reduce the 256 per-block partials (8 groups x 32 blocks each)
        float s = 0.f, s2 = 0.f;
        if (fi < fc) {
            for (int blk = g; blk < SBLK; blk += 8) {
                s  += p.sum[(size_t)blk * 2048 + f0 + fi];
                s2 += p.sumsq[(size_t)blk * 2048 + f0 + fi];
            }
        }
        rs[g][fi] = s; rs2[g][fi] = s2;
    }
    __syncthreads();
    if (t < 32) {
        float c = 0.f;
        if (t < fc) {
            float sm = 0.f, sq = 0.f;
            #pragma unroll
            for (int gg = 0; gg < 8; gg++) { sm += rs[gg][t]; sq += rs2[gg][t]; }
            int f = f0 + t;
            float mu  = sm * (1.f / 8192.f);
            float var = sq * (1.f / 8192.f) - mu * mu;
            float a = p.gamma[f] * rsqrtf(var + 1e-5f);
            p.a[f] = a;
            c = p.beta[f] - mu * a;
        }
        c_sh[t] = c;
    }
    __syncthreads();
    int h = t & 31; g = t >> 5;
    float s = 0.f;
    for (int fi2 = g; fi2 < fc; fi2 += 8)
        s += c_sh[fi2] * p.W1[(size_t)(f0 + fi2) * 32 + h];
    red[g][h] = s;
    __syncthreads();
    if (t < 32) {
        float tot = 0.f;
        #pragma unroll
        for (int gg = 0; gg < 8; gg++) tot += red[gg][t];
        atomicAdd(&p.b1p[t], tot);
    }
}

// ---------------- Subnet MLP: 32 rows/block, 4h x 8r tile, k-split 8 ----------------
__global__ void __launch_bounds__(256) subnet3_kernel(SubP3 P) {
    const SubP p = P.s[blockIdx.y];
    const int F = p.F;
    __shared__ float smem[8832];
    float* Red = smem;            // 3 x [32][36] = 3456
    float* H1  = smem + 3456;     // [32][36] -> 4608
    float* W23 = smem + 4608;     // [32][33] -> 5664
    float* H2  = smem;            // [32][36]

    int t = threadIdx.x;
    int row0 = blockIdx.x * 32;
    int kg = t >> 6;
    int lane = t & 63;
    int hg = lane & 7, h0 = hg * 4;
    int rg = (lane >> 3) & 3;
    int ks = lane >> 5;

    float acc[4][8] = {};         // [hi][ri], rows rg + 4*ri

    if (F == 1024) {
        float* Xt = smem;             // [32][132] = 4224
        float* Wt = smem + 4224;      // [128][36] = 4608 -> 8832
        int xr = t >> 3, xc = (t & 7) * 16;
        int wk = t >> 1, wh = (t & 1) * 16;
        const float* xbase = p.x + (size_t)row0 * 1024;
        f32x4 xp[4], wp[4]; float av;
        #pragma unroll
        for (int i = 0; i < 4; i++) xp[i] = *(const f32x4*)&xbase[(size_t)xr * 1024 + xc + i * 4];
        #pragma unroll
        for (int i = 0; i < 4; i++) wp[i] = *(const f32x4*)&p.W1[(size_t)wk * 32 + wh + i * 4];
        av = p.a[wk];
        int kb = (kg * 2 + ks) * 16;
        for (int c = 0; c < 8; c++) {
            __syncthreads();          // prev chunk's reads done
            #pragma unroll
            for (int i = 0; i < 4; i++) *(f32x4*)&Xt[xr * 132 + xc + i * 4] = xp[i];
            #pragma unroll
            for (int i = 0; i < 4; i++) *(f32x4*)&Wt[wk * 36 + wh + i * 4] = wp[i] * av;
            if (c < 7) {
                int k0 = (c + 1) * 128;
                #pragma unroll
                for (int i = 0; i < 4; i++) xp[i] = *(const f32x4*)&xbase[(size_t)xr * 1024 + k0 + xc + i * 4];
                #pragma unroll
                for (int i = 0; i < 4; i++) wp[i] = *(const f32x4*)&p.W1[(size_t)(k0 + wk) * 32 + wh + i * 4];
                av = p.a[k0 + wk];
            }
            __syncthreads();          // tiles ready
            #pragma unroll
            for (int s = 0; s < 4; s++) {
                int kk = kb + s * 4;
                f32x4 wv[4], xv[8];
                #pragma unroll
                for (int j = 0; j < 4; j++)  wv[j]  = *(const f32x4*)&Wt[(kk + j) * 36 + h0];
                #pragma unroll
                for (int ri = 0; ri < 8; ri++) xv[ri] = *(const f32x4*)&Xt[(rg + 4 * ri) * 132 + kk];
                #pragma unroll
                for (int j = 0; j < 4; j++)
                    #pragma unroll
                    for (int hi = 0; hi < 4; hi++) {
                        float w = wv[j][hi];
                        #pragma unroll
                        for (int ri = 0; ri < 8; ri++)
                            acc[hi][ri] = fmaf(w, xv[ri][j], acc[hi][ri]);
                    }
            }
        }
    } else {
        float* Xt = smem;             // [32][68]
        float* Wt = smem + 2176;      // [64][36]
        int kbase = (kg * 2 + ks) * 8;
        for (int k0 = 0; k0 < F; k0 += 64) {
            int kc = F - k0; if (kc > 64) kc = 64;
            int kcp = (kc + 3) & ~3;
            __syncthreads();
            for (int idx = t; idx < 32 * kcp; idx += 256) {
                int r = idx / kcp, kk = idx - r * kcp;
                Xt[r * 68 + kk] = (kk < kc) ? p.x[(size_t)(row0 + r) * F + k0 + kk] : 0.f;
            }
            for (int idx = t; idx < kcp * 32; idx += 256) {
                int kk = idx >> 5, hh = idx & 31;
                Wt[kk * 36 + hh] = (kk < kc) ? p.a[k0 + kk] * p.W1[(size_t)(k0 + kk) * 32 + hh] : 0.f;
            }
            __syncthreads();
            #pragma unroll
            for (int s = 0; s < 2; s++) {
                int kk = kbase + s * 4;
                if (kk < kcp) {
                    f32x4 wv[4], xv[8];
                    #pragma unroll
                    for (int j = 0; j < 4; j++)  wv[j]  = *(const f32x4*)&Wt[(kk + j) * 36 + h0];
                    #pragma unroll
                    for (int ri = 0; ri < 8; ri++) xv[ri] = *(const f32x4*)&Xt[(rg + 4 * ri) * 68 + kk];
                    #pragma unroll
                    for (int j = 0; j < 4; j++)
                        #pragma unroll
                        for (int hi = 0; hi < 4; hi++) {
                            float w = wv[j][hi];
                            #pragma unroll
                            for (int ri = 0; ri < 8; ri++)
                                acc[hi][ri] = fmaf(w, xv[ri][j], acc[hi][ri]);
                        }
                }
            }
        }
    }
    // merge the two lane-half k-slices in-register
    #pragma unroll
    for (int hi = 0; hi < 4; hi++)
        #pragma unroll
        for (int ri = 0; ri < 8; ri++)
            acc[hi][ri] += __shfl_xor(acc[hi][ri], 32);
    __syncthreads();                              // S1: Xt/Wt dead
    if (kg > 0 && ks == 0) {
        #pragma unroll
        for (int ri = 0; ri < 8; ri++) {
            int r = rg + 4 * ri;
            f32x4 v = {acc[0][ri], acc[1][ri], acc[2][ri], acc[3][ri]};
            *(f32x4*)&Red[(kg - 1) * 1152 + r * 36 + h0] = v;
        }
    }
    for (int idx = t; idx < 1024; idx += 256) W23[(idx >> 5) * 33 + (idx & 31)] = p.W2[idx];
    __syncthreads();                              // S2: Red + W2 ready
    if (kg == 0 && ks == 0) {
        f32x4 b;
        #pragma unroll
        for (int hi = 0; hi < 4; hi++) b[hi] = p.b1[h0 + hi] + p.b1p[h0 + hi];
        #pragma unroll
        for (int ri = 0; ri < 8; ri++) {
            int r = rg + 4 * ri;
            f32x4 v = {acc[0][ri], acc[1][ri], acc[2][ri], acc[3][ri]};
            #pragma unroll
            for (int pp = 0; pp < 3; pp++)
                v += *(const f32x4*)&Red[pp * 1152 + r * 36 + h0];
            v += b;
            #pragma unroll
            for (int hi = 0; hi < 4; hi++)
                H1[r * 36 + h0 + hi] = fmaxf(v[hi], 0.f);
        }
    }
    __syncthreads();                              // S3: H1 ready
    int h = t & 31, rq = t >> 5;                  // 8 groups x 4 rows
    {
        float a2[4] = {};
        for (int q = 0; q < 32; q++) {
            float w = W23[q * 33 + h];
            #pragma unroll
            for (int i = 0; i < 4; i++) a2[i] += H1[(rq * 4 + i) * 36 + q] * w;
        }
        float bv = p.b2[h];
        #pragma unroll
        for (int i = 0; i < 4; i++) H2[(rq * 4 + i) * 36 + h] = fmaxf(a2[i] + bv, 0.f);
    }
    __syncthreads();                              // S4
    for (int idx = t; idx < 1024; idx += 256) W23[(idx >> 5) * 33 + (idx & 31)] = p.W3[idx];
    __syncthreads();                              // S5
    {
        float a3[4] = {};
        for (int q = 0; q < 32; q++) {
            float w = W23[q * 33 + h];
            #pragma unroll
            for (int i = 0; i < 4; i++) a3[i] += H2[(rq * 4 + i) * 36 + q] * w;
        }
        float bv = p.b3[h];
        #pragma unroll
        for (int i = 0; i < 4; i++)
            p.hout[(size_t)(row0 + rq * 4 + i) * 32 + h] = fmaxf(a3[i] + bv, 0.f);
    }
}

// ---------------- p1 build (4 rows/block, wave-per-row) + W2t transpose, one launch -------
__global__ void __launch_bounds__(256) build_both(const float* __restrict__ mk_h,
                           const float* __restrict__ us_h,
                           bf16* __restrict__ p1,
                           const float* __restrict__ Wf1, bf16* __restrict__ W2t) {
    int blk = blockIdx.x;
    int t = threadIdx.x;
    if (blk < NB / 4) {
        int r = t >> 6, lane = t & 63;
        int b = blk * 4 + r;
        __shared__ float mk1[4][34], us1[4][34];
        if (lane == 0) { mk1[r][0] = 1.f; us1[r][0] = 1.f; }
        if (lane < 32) mk1[r][lane + 1] = mk_h[(size_t)b * 32 + lane];
        else           us1[r][lane - 31] = us_h[(size_t)b * 32 + (lane - 32)];
        __syncthreads();
        #pragma unroll
        for (int c = 0; c < 3; c++) {
            int chunk = lane + 64 * c;
            if (chunk < 144) {                 // 144*8 = 1152 = KP
                int base = chunk * 8;
                s16x8 v;
                #pragma unroll
                for (int e = 0; e < 8; e++) {
                    int idx = base + e;
                    float val = 0.f;
                    if (idx < 1089) {
                        int k = idx / 33, i = idx - k * 33;
                        val = mk1[r][k] * us1[r][i];
                    }
                    __hip_bfloat16 hb = __float2bfloat16(val);
                    v[e] = *(short*)&hb;
                }
                *(s16x8*)(p1 + (size_t)b * KP + base) = v;
            }
        }
    } else {
        int kj = blk - NB / 4;
        int k = kj / 33, j = kj - k * 33;
        __shared__ float tile[1089];
        const float* src = Wf1 + (size_t)k * 35937 + (size_t)j * 1089;  // [i][o] contiguous
        for (int idx = t; idx < 1089; idx += 256) tile[idx] = src[idx];
        __syncthreads();
        for (int idx = t; idx < 1089; idx += 256) {
            int o = idx / 33, i = idx - o * 33;
            W2t[(size_t)(j * 33 + o) * KP + k * 33 + i] = __float2bfloat16(tile[i * 33 + o]);
        }
        if (k == 0) {
            // zero the K-pad (kk 1089..1151) for this j's 33 n-rows
            bf16 z = __float2bfloat16(0.f);
            for (int idx = t; idx < 33 * 63; idx += 256) {
                int o = idx / 63, kkp = 1089 + idx - o * 63;
                W2t[(size_t)(j * 33 + o) * KP + kkp] = z;
            }
        }
    }
}

// ---------------- Main GEMM: S[8192,1152] = p1 @ W2t^T ----------------
// R2 configuration (best measured: 42.5us, conflicts 0) -- FROZEN this round.
__global__ void __launch_bounds__(256) gemm_kernel(const bf16* __restrict__ A,   // [NB][KP]
                                                   const bf16* __restrict__ Bt,  // [NP][KP]
                                                   bf16* __restrict__ S) {       // [NB][NP]
    __shared__ __align__(16) bf16 As[2][128 * 32];
    __shared__ __align__(16) bf16 Bs[2][128 * 32];
    int t = threadIdx.x;
    int m0 = blockIdx.x * 128;
    int n0 = blockIdx.y * 128;
    int wave = t >> 6, lane = t & 63;
    int wm = (wave & 1) * 64, wn = (wave >> 1) * 64;
    int fr = lane & 15;
    int q  = lane >> 4;
    int rsw = (fr >> 1) & 3;

    int lr = lane >> 2;
    int sslot = (lane & 3) ^ ((lane >> 3) & 3);
    const bf16* Ag = A  + (size_t)(m0 + wave * 32 + lr) * KP + sslot * 8;
    const bf16* Bg = Bt + (size_t)(n0 + wave * 32 + lr) * KP + sslot * 8;

    f32x4 acc[4][4] = {};

    auto stage = [&](int buf, int k0) {
        bf16* Ad = &As[buf][wave * 1024];
        bf16* Bd = &Bs[buf][wave * 1024];
        __builtin_amdgcn_global_load_lds(
            (const __attribute__((address_space(1))) void*)(Ag + k0),
            (__attribute__((address_space(3))) void*)(Ad), 16, 0, 0);
        __builtin_amdgcn_global_load_lds(
            (const __attribute__((address_space(1))) void*)(Ag + k0 + (size_t)16 * KP),
            (__attribute__((address_space(3))) void*)(Ad + 16 * 32), 16, 0, 0);
        __builtin_amdgcn_global_load_lds(
            (const __attribute__((address_space(1))) void*)(Bg + k0),
            (__attribute__((address_space(3))) void*)(Bd), 16, 0, 0);
        __builtin_amdgcn_global_load_lds(
            (const __attribute__((address_space(1))) void*)(Bg + k0 + (size_t)16 * KP),
            (__attribute__((address_space(3))) void*)(Bd + 16 * 32), 16, 0, 0);
    };

    stage(0, 0);
    __syncthreads();
    int cur = 0;
    for (int ks = 0; ks < NK; ks++) {
        if (ks < NK - 1) stage(cur ^ 1, (ks + 1) * 32);
        const bf16* Ab = &As[cur][0];
        const bf16* Bb = &Bs[cur][0];
        s16x8 bfr[4];
        #pragma unroll
        for (int nt = 0; nt < 4; nt++) {
            int row = wn + nt * 16 + fr;
            bfr[nt] = *(const s16x8*)(Bb + row * 32 + ((q ^ rsw) * 8));
        }
        #pragma unroll
        for (int mt = 0; mt < 4; mt++) {
            int row = wm + mt * 16 + fr;
            s16x8 af = *(const s16x8*)(Ab + row * 32 + ((q ^ rsw) * 8));
            #pragma unroll
            for (int nt = 0; nt < 4; nt++)
                acc[mt][nt] = __builtin_amdgcn_mfma_f32_16x16x32_bf16(af, bfr[nt], acc[mt][nt], 0, 0, 0);
        }
        __syncthreads();
        cur ^= 1;
    }
    int col = lane & 15, rowg = (lane >> 4) * 4;
    #pragma unroll
    for (int mt = 0; mt < 4; mt++)
        #pragma unroll
        for (int nt = 0; nt < 4; nt++)
            #pragma unroll
            for (int r = 0; r < 4; r++) {
                int gr = m0 + wm + mt * 16 + rowg + r;
                int gc = n0 + wn + nt * 16 + col;
                S[(size_t)gr * NP + gc] = __float2bfloat16(acc[mt][nt][r]);
            }
}

// ---------------- Epilogue: stage S rows as bf16 in LDS, contract j, 33x5 + sigmoid ----------
__global__ void __launch_bounds__(256) epilogue_kernel(const bf16* __restrict__ S,
                                const float* __restrict__ cd_h,
                                const float* __restrict__ bf1, const float* __restrict__ Wf2,
                                const float* __restrict__ bf2, float* __restrict__ out) {
    int w = threadIdx.x >> 6;
    int lane = threadIdx.x & 63;
    int b = blockIdx.x * 4 + w;
    __shared__ __align__(16) unsigned short Sl[4][1152];
    __shared__ float cdsh[4][33];
    __shared__ float hsh[4][40];
    const bf16* Srow = S + (size_t)b * NP;
    #pragma unroll
    for (int pass = 0; pass < 3; pass++) {
        int idx = lane + pass * 64;
        if (idx < 144)
            *(s16x8*)&Sl[w][idx * 8] = *(const s16x8*)(Srow + idx * 8);
    }
    if (lane == 0) cdsh[w][0] = 1.f;
    if (lane < 32) cdsh[w][lane + 1] = cd_h[(size_t)b * 32 + lane];
    __syncthreads();
    if (lane < 33) {
        float acc = bf1[lane];
        #pragma unroll 3
        for (int j = 0; j < 33; j++) {
            unsigned short sv = Sl[w][j * 33 + lane];
            acc += cdsh[w][j] * __bfloat162float(*(bf16*)&sv);
        }
        hsh[w][lane] = fmaxf(acc, 0.f);
    }
    __syncthreads();
    if (lane < 5) {
        float o = bf2[lane];
        for (int q = 0; q < 33; q++) o += hsh[w][q] * Wf2[q * 5 + lane];
        out[(size_t)b * 5 + lane] = 1.f / (1.f + expf(-o));
    }
}

extern "C" void kernel_launch(void* const* d_in, const int* in_sizes, int n_in,
                              void* d_out, int out_size, void* d_ws, size_t ws_size,
                              hipStream_t stream) {
    const float* US_x     = (const float*)d_in[0];
    const float* CDFI_x   = (const float*)d_in[1];
    const float* marker_x = (const float*)d_in[2];
    const float* Wf1      = (const float*)d_in[27];
    const float* bf1      = (const float*)d_in[28];
    const float* Wf2      = (const float*)d_in[29];
    const float* bf2      = (const float*)d_in[30];
    float* out = (float*)d_out;

    char* ws = (char*)d_ws;
    size_t off = 0;
    auto alloc = [&](size_t bytes) -> void* {
        void* p = ws + off;
        off = (off + bytes + 255) & ~(size_t)255;
        return p;
    };

    float* b1p_buf  = (float*)alloc(3 * 128 * sizeof(float));                 // zeroed
    float* pstat    = (float*)alloc((size_t)3 * SBLK * 2048 * sizeof(float)); // partials
    float* a_buf[3], *h_buf[3];
    for (int i = 0; i < 3; i++) {
        a_buf[i] = (float*)alloc(1024 * 4);
        h_buf[i] = (float*)alloc((size_t)NB * 32 * 4);
    }
    bf16*  p1   = (bf16*)alloc((size_t)NB * KP * 2);
    bf16*  W2t  = (bf16*)alloc((size_t)NP * KP * 2);
    bf16*  S    = (bf16*)alloc((size_t)NB * NP * 2);

    SubP3 P;
    const float* xs[3] = {US_x, CDFI_x, marker_x};
    int Fs[3] = {1024, 1024, 10};
    for (int i = 0; i < 3; i++) {
        int base = 3 + i * 8;
        P.s[i].x     = xs[i];
        P.s[i].gamma = (const float*)d_in[base + 0];
        P.s[i].beta  = (const float*)d_in[base + 1];
        P.s[i].W1    = (const float*)d_in[base + 2];
        P.s[i].b1    = (const float*)d_in[base + 3];
        P.s[i].W2    = (const float*)d_in[base + 4];
        P.s[i].b2    = (const float*)d_in[base + 5];
        P.s[i].W3    = (const float*)d_in[base + 6];
        P.s[i].b3    = (const float*)d_in[base + 7];
        P.s[i].sum   = pstat + (size_t)i * SBLK * 2048;
        P.s[i].sumsq = pstat + (size_t)i * SBLK * 2048 + 1024;
        P.s[i].b1p   = b1p_buf + i * 128;
        P.s[i].a     = a_buf[i];
        P.s[i].hout  = h_buf[i];
        P.s[i].F     = Fs[i];
    }

    float* us_h = h_buf[0];
    float* cd_h = h_buf[1];
    float* mk_h = h_buf[2];

    hipMemsetAsync(b1p_buf, 0, 3 * 128 * sizeof(float), stream);

    stats3_kernel<<<dim3(SBLK, 1, 3), 256, 0, stream>>>(P);
    prep3_kernel<<<dim3(32, 3), 256, 0, stream>>>(P);
    subnet3_kernel<<<dim3(256, 3), 256, 0, stream>>>(P);

    build_both<<<NB / 4 + 1089, 256, 0, stream>>>(mk_h, us_h, p1, Wf1, W2t);

    gemm_kernel<<<dim3(NB / 128, NP / 128), 256, 0, stream>>>(p1, W2t, S);

    epilogue_kernel<<<NB / 4, 256, 0, stream>>>(S, cd_h, bf1, Wf2, bf2, out);
}

// Round 9
// 246.364 us; speedup vs baseline: 1.3061x; 1.0349x over previous
//
#include <hip/hip_runtime.h>
#include <hip/hip_bf16.h>
#include <math.h>

typedef __hip_bfloat16 bf16;
typedef __attribute__((ext_vector_type(4))) float f32x4;
typedef __attribute__((ext_vector_type(8))) short s16x8;

#define NB 8192
#define KP 1152   // padded K: 1089 -> 18*64
#define NP 1152   // padded N: 1089 -> 8*144
#define NKT 18    // K-tiles of 64
#define SBLK 256  // stats blocks per subnet (32 rows each)

struct SubP {
    const float* x; const float* gamma; const float* beta;
    const float* W1; const float* b1; const float* W2; const float* b2;
    const float* W3; const float* b3;
    float* sum; float* sumsq; float* a; float* b1p; float* hout;
    int F;
};
struct SubP3 { SubP s[3]; };

// ---------------- BatchNorm stats: 32 rows/block, grid (256,3), contention-free ----------
__global__ void __launch_bounds__(256) stats3_kernel(SubP3 P) {
    const SubP p = P.s[blockIdx.z];
    int t = threadIdx.x;
    int blk = blockIdx.x;
    int row0 = blk * 32;
    if (p.F == 1024) {
        f32x4 s = {0.f, 0.f, 0.f, 0.f}, s2 = {0.f, 0.f, 0.f, 0.f};
        const float* xp = p.x + (size_t)row0 * 1024 + t * 4;
        #pragma unroll 8
        for (int r = 0; r < 32; r++) {
            f32x4 v = *(const f32x4*)(xp + (size_t)r * 1024);
            s += v; s2 += v * v;
        }
        int f = t * 4;
        *(f32x4*)&p.sum[(size_t)blk * 2048 + f]   = s;
        *(f32x4*)&p.sumsq[(size_t)blk * 2048 + f] = s2;
    } else {
        __shared__ float ls[16], ls2[16];
        if (t < 16) { ls[t] = 0.f; ls2[t] = 0.f; }
        __syncthreads();
        int F = p.F;
        for (int idx = t; idx < 32 * F; idx += 256) {
            float v = p.x[(size_t)row0 * F + idx];
            int f = idx % 10;            // row0*F = blk*320 ≡ 0 (mod 10)
            atomicAdd(&ls[f], v);        // LDS-scope only
            atomicAdd(&ls2[f], v * v);
        }
        __syncthreads();
        if (t < F) {
            p.sum[(size_t)blk * 2048 + t]   = ls[t];
            p.sumsq[(size_t)blk * 2048 + t] = ls2[t];
        }
    }
}

// ---------------- finalize stats: reduce 256 partials; a[f]; c@W1 fold -> atomic b1p ----
__global__ void prep3_kernel(SubP3 P) {
    const SubP p = P.s[blockIdx.y];
    int f0 = blockIdx.x * 32;
    if (f0 >= p.F) return;
    int t = threadIdx.x;
    __shared__ float c_sh[32];
    __shared__ float red[8][33];
    __shared__ float rs[8][33], rs2[8][33];
    int fc = p.F - f0; if (fc > 32) fc = 32;
    int fi = t & 31, g = t >> 5;
    {
        float s = 0.f, s2 = 0.f;
        if (fi < fc) {
            for (int blk = g; blk < SBLK; blk += 8) {
                s  += p.sum[(size_t)blk * 2048 + f0 + fi];
                s2 += p.sumsq[(size_t)blk * 2048 + f0 + fi];
            }
        }
        rs[g][fi] = s; rs2[g][fi] = s2;
    }
    __syncthreads();
    if (t < 32) {
        float c = 0.f;
        if (t < fc) {
            float sm = 0.f, sq = 0.f;
            #pragma unroll
            for (int gg = 0; gg < 8; gg++) { sm += rs[gg][t]; sq += rs2[gg][t]; }
            int f = f0 + t;
            float mu  = sm * (1.f / 8192.f);
            float var = sq * (1.f / 8192.f) - mu * mu;
            float a = p.gamma[f] * rsqrtf(var + 1e-5f);
            p.a[f] = a;
            c = p.beta[f] - mu * a;
        }
        c_sh[t] = c;
    }
    __syncthreads();
    int h = t & 31; g = t >> 5;
    float s = 0.f;
    for (int fi2 = g; fi2 < fc; fi2 += 8)
        s += c_sh[fi2] * p.W1[(size_t)(f0 + fi2) * 32 + h];
    red[g][h] = s;
    __syncthreads();
    if (t < 32) {
        float tot = 0.f;
        #pragma unroll
        for (int gg = 0; gg < 8; gg++) tot += red[gg][t];
        atomicAdd(&p.b1p[t], tot);
    }
}

// ---------------- Subnet MLP: 32 rows/block, 4h x 8r tile, k-split 8 ----------------
__global__ void __launch_bounds__(256) subnet3_kernel(SubP3 P) {
    const SubP p = P.s[blockIdx.y];
    const int F = p.F;
    __shared__ float smem[8832];
    float* Red = smem;            // 3 x [32][36] = 3456
    float* H1  = smem + 3456;     // [32][36] -> 4608
    float* W23 = smem + 4608;     // [32][33] -> 5664
    float* H2  = smem;            // [32][36]

    int t = threadIdx.x;
    int row0 = blockIdx.x * 32;
    int kg = t >> 6;
    int lane = t & 63;
    int hg = lane & 7, h0 = hg * 4;
    int rg = (lane >> 3) & 3;
    int ks = lane >> 5;

    float acc[4][8] = {};         // [hi][ri], rows rg + 4*ri

    if (F == 1024) {
        float* Xt = smem;             // [32][132] = 4224
        float* Wt = smem + 4224;      // [128][36] = 4608 -> 8832
        int xr = t >> 3, xc = (t & 7) * 16;
        int wk = t >> 1, wh = (t & 1) * 16;
        const float* xbase = p.x + (size_t)row0 * 1024;
        f32x4 xp[4], wp[4]; float av;
        #pragma unroll
        for (int i = 0; i < 4; i++) xp[i] = *(const f32x4*)&xbase[(size_t)xr * 1024 + xc + i * 4];
        #pragma unroll
        for (int i = 0; i < 4; i++) wp[i] = *(const f32x4*)&p.W1[(size_t)wk * 32 + wh + i * 4];
        av = p.a[wk];
        int kb = (kg * 2 + ks) * 16;
        for (int c = 0; c < 8; c++) {
            __syncthreads();          // prev chunk's reads done
            #pragma unroll
            for (int i = 0; i < 4; i++) *(f32x4*)&Xt[xr * 132 + xc + i * 4] = xp[i];
            #pragma unroll
            for (int i = 0; i < 4; i++) *(f32x4*)&Wt[wk * 36 + wh + i * 4] = wp[i] * av;
            if (c < 7) {
                int k0 = (c + 1) * 128;
                #pragma unroll
                for (int i = 0; i < 4; i++) xp[i] = *(const f32x4*)&xbase[(size_t)xr * 1024 + k0 + xc + i * 4];
                #pragma unroll
                for (int i = 0; i < 4; i++) wp[i] = *(const f32x4*)&p.W1[(size_t)(k0 + wk) * 32 + wh + i * 4];
                av = p.a[k0 + wk];
            }
            __syncthreads();          // tiles ready
            #pragma unroll
            for (int s = 0; s < 4; s++) {
                int kk = kb + s * 4;
                f32x4 wv[4], xv[8];
                #pragma unroll
                for (int j = 0; j < 4; j++)  wv[j]  = *(const f32x4*)&Wt[(kk + j) * 36 + h0];
                #pragma unroll
                for (int ri = 0; ri < 8; ri++) xv[ri] = *(const f32x4*)&Xt[(rg + 4 * ri) * 132 + kk];
                #pragma unroll
                for (int j = 0; j < 4; j++)
                    #pragma unroll
                    for (int hi = 0; hi < 4; hi++) {
                        float w = wv[j][hi];
                        #pragma unroll
                        for (int ri = 0; ri < 8; ri++)
                            acc[hi][ri] = fmaf(w, xv[ri][j], acc[hi][ri]);
                    }
            }
        }
    } else {
        float* Xt = smem;             // [32][68]
        float* Wt = smem + 2176;      // [64][36]
        int kbase = (kg * 2 + ks) * 8;
        for (int k0 = 0; k0 < F; k0 += 64) {
            int kc = F - k0; if (kc > 64) kc = 64;
            int kcp = (kc + 3) & ~3;
            __syncthreads();
            for (int idx = t; idx < 32 * kcp; idx += 256) {
                int r = idx / kcp, kk = idx - r * kcp;
                Xt[r * 68 + kk] = (kk < kc) ? p.x[(size_t)(row0 + r) * F + k0 + kk] : 0.f;
            }
            for (int idx = t; idx < kcp * 32; idx += 256) {
                int kk = idx >> 5, hh = idx & 31;
                Wt[kk * 36 + hh] = (kk < kc) ? p.a[k0 + kk] * p.W1[(size_t)(k0 + kk) * 32 + hh] : 0.f;
            }
            __syncthreads();
            #pragma unroll
            for (int s = 0; s < 2; s++) {
                int kk = kbase + s * 4;
                if (kk < kcp) {
                    f32x4 wv[4], xv[8];
                    #pragma unroll
                    for (int j = 0; j < 4; j++)  wv[j]  = *(const f32x4*)&Wt[(kk + j) * 36 + h0];
                    #pragma unroll
                    for (int ri = 0; ri < 8; ri++) xv[ri] = *(const f32x4*)&Xt[(rg + 4 * ri) * 68 + kk];
                    #pragma unroll
                    for (int j = 0; j < 4; j++)
                        #pragma unroll
                        for (int hi = 0; hi < 4; hi++) {
                            float w = wv[j][hi];
                            #pragma unroll
                            for (int ri = 0; ri < 8; ri++)
                                acc[hi][ri] = fmaf(w, xv[ri][j], acc[hi][ri]);
                        }
                }
            }
        }
    }
    // merge the two lane-half k-slices in-register
    #pragma unroll
    for (int hi = 0; hi < 4; hi++)
        #pragma unroll
        for (int ri = 0; ri < 8; ri++)
            acc[hi][ri] += __shfl_xor(acc[hi][ri], 32);
    __syncthreads();                              // S1: Xt/Wt dead
    if (kg > 0 && ks == 0) {
        #pragma unroll
        for (int ri = 0; ri < 8; ri++) {
            int r = rg + 4 * ri;
            f32x4 v = {acc[0][ri], acc[1][ri], acc[2][ri], acc[3][ri]};
            *(f32x4*)&Red[(kg - 1) * 1152 + r * 36 + h0] = v;
        }
    }
    for (int idx = t; idx < 1024; idx += 256) W23[(idx >> 5) * 33 + (idx & 31)] = p.W2[idx];
    __syncthreads();                              // S2: Red + W2 ready
    if (kg == 0 && ks == 0) {
        f32x4 b;
        #pragma unroll
        for (int hi = 0; hi < 4; hi++) b[hi] = p.b1[h0 + hi] + p.b1p[h0 + hi];
        #pragma unroll
        for (int ri = 0; ri < 8; ri++) {
            int r = rg + 4 * ri;
            f32x4 v = {acc[0][ri], acc[1][ri], acc[2][ri], acc[3][ri]};
            #pragma unroll
            for (int pp = 0; pp < 3; pp++)
                v += *(const f32x4*)&Red[pp * 1152 + r * 36 + h0];
            v += b;
            #pragma unroll
            for (int hi = 0; hi < 4; hi++)
                H1[r * 36 + h0 + hi] = fmaxf(v[hi], 0.f);
        }
    }
    __syncthreads();                              // S3: H1 ready
    int h = t & 31, rq = t >> 5;                  // 8 groups x 4 rows
    {
        float a2[4] = {};
        for (int q = 0; q < 32; q++) {
            float w = W23[q * 33 + h];
            #pragma unroll
            for (int i = 0; i < 4; i++) a2[i] += H1[(rq * 4 + i) * 36 + q] * w;
        }
        float bv = p.b2[h];
        #pragma unroll
        for (int i = 0; i < 4; i++) H2[(rq * 4 + i) * 36 + h] = fmaxf(a2[i] + bv, 0.f);
    }
    __syncthreads();                              // S4
    for (int idx = t; idx < 1024; idx += 256) W23[(idx >> 5) * 33 + (idx & 31)] = p.W3[idx];
    __syncthreads();                              // S5
    {
        float a3[4] = {};
        for (int q = 0; q < 32; q++) {
            float w = W23[q * 33 + h];
            #pragma unroll
            for (int i = 0; i < 4; i++) a3[i] += H2[(rq * 4 + i) * 36 + q] * w;
        }
        float bv = p.b3[h];
        #pragma unroll
        for (int i = 0; i < 4; i++)
            p.hout[(size_t)(row0 + rq * 4 + i) * 32 + h] = fmaxf(a3[i] + bv, 0.f);
    }
}

// ---------------- p1 build (4 rows/block, wave-per-row) + W2t transpose, one launch -------
__global__ void __launch_bounds__(256) build_both(const float* __restrict__ mk_h,
                           const float* __restrict__ us_h,
                           bf16* __restrict__ p1,
                           const float* __restrict__ Wf1, bf16* __restrict__ W2t) {
    int blk = blockIdx.x;
    int t = threadIdx.x;
    if (blk < NB / 4) {
        int r = t >> 6, lane = t & 63;
        int b = blk * 4 + r;
        __shared__ float mk1[4][34], us1[4][34];
        if (lane == 0) { mk1[r][0] = 1.f; us1[r][0] = 1.f; }
        if (lane < 32) mk1[r][lane + 1] = mk_h[(size_t)b * 32 + lane];
        else           us1[r][lane - 31] = us_h[(size_t)b * 32 + (lane - 32)];
        __syncthreads();
        #pragma unroll
        for (int c = 0; c < 3; c++) {
            int chunk = lane + 64 * c;
            if (chunk < 144) {                 // 144*8 = 1152 = KP
                int base = chunk * 8;
                s16x8 v;
                #pragma unroll
                for (int e = 0; e < 8; e++) {
                    int idx = base + e;
                    float val = 0.f;
                    if (idx < 1089) {
                        int k = idx / 33, i = idx - k * 33;
                        val = mk1[r][k] * us1[r][i];
                    }
                    __hip_bfloat16 hb = __float2bfloat16(val);
                    v[e] = *(short*)&hb;
                }
                *(s16x8*)(p1 + (size_t)b * KP + base) = v;
            }
        }
    } else {
        int kj = blk - NB / 4;
        int k = kj / 33, j = kj - k * 33;
        __shared__ float tile[1089];
        const float* src = Wf1 + (size_t)k * 35937 + (size_t)j * 1089;  // [i][o] contiguous
        for (int idx = t; idx < 1089; idx += 256) tile[idx] = src[idx];
        __syncthreads();
        for (int idx = t; idx < 1089; idx += 256) {
            int o = idx / 33, i = idx - o * 33;
            W2t[(size_t)(j * 33 + o) * KP + k * 33 + i] = __float2bfloat16(tile[i * 33 + o]);
        }
        if (k == 0) {
            // zero the K-pad (kk 1089..1151) for this j's 33 n-rows
            bf16 z = __float2bfloat16(0.f);
            for (int idx = t; idx < 33 * 63; idx += 256) {
                int o = idx / 63, kkp = 1089 + idx - o * 63;
                W2t[(size_t)(j * 33 + o) * KP + kkp] = z;
            }
        }
    }
}

// ---------------- Main GEMM: S[8192,1152] = p1 @ W2t^T -- 8-phase-family port ----------
// BM=256 x BN=144, BK=64, 512 threads (8 waves, 2/SIMD), grid (32,8)=256 blocks = 1/CU.
// T3+T4 schedule (m201 family): per K-tile T two sub-phases of 18 MFMA each:
//   phA: issue stage-A(T+1) -> vmcnt(4) [tile T's 7 loads landed; T+1's 4 A-loads in
//        flight] -> raw s_barrier -> ds_read ks-half-0 -> setprio(1) 18 MFMA setprio(0)
//   phB: issue stage-B(T+1) -> ds_read ks-half-1 -> 18 MFMA -> raw s_barrier
// vmcnt is NEVER 0 in the main loop (T4); __syncthreads (vmcnt(0) drain) never used.
// Staging uniform 7 gload_lds/wave/K-tile (4 A + 3 B; Bs padded to 192 rows so B=3/wave
// exactly -- pad rows read allocated garbage, never consumed by MFMA).
// Hazards: stage into buf b^1 issued only after the end-of-tile barrier that retired all
// waves' reads of b^1; asm volatile ""::"memory" after barriers = compiler fence.
// Swizzle: r1-verified BK=64 algebra (stage sslot=(lane&7)^(lane>>3); read slot^(fr&7));
// measured 0 bank conflicts.
__global__ void __launch_bounds__(512) gemm_kernel(const bf16* __restrict__ A,   // [NB][KP]
                                                   const bf16* __restrict__ Bt,  // [NP][KP]
                                                   bf16* __restrict__ S) {       // [NB][NP]
    __shared__ __align__(16) bf16 As[2][256 * 64];   // 64 KB
    __shared__ __align__(16) bf16 Bs[2][192 * 64];   // 48 KB (rows 144..191 = pad)
    int t = threadIdx.x;
    int wv = t >> 6, lane = t & 63;
    int m0 = blockIdx.x * 256;
    int n0 = blockIdx.y * 144;
    int fr = lane & 15;
    int q  = lane >> 4;                  // 16B slot within 32-elem k-half
    int lr8 = lane >> 3;
    int sslot = (lane & 7) ^ lr8;        // pre-swizzled source slot (both-sides rule 21)

    const bf16* Ag = A  + (size_t)(m0 + wv * 32 + lr8) * KP + sslot * 8;
    const bf16* Bg = Bt + (size_t)(n0 + wv * 24 + lr8) * KP + sslot * 8;

    f32x4 acc[2][9] = {};

    auto stageA = [&](int buf, int T) {        // 4 instrs: wave's 32 A-rows
        bf16* Ad = &As[buf][wv * 32 * 64];
        const bf16* s = Ag + T * 64;
        #pragma unroll
        for (int i = 0; i < 4; i++)
            __builtin_amdgcn_global_load_lds(
                (const __attribute__((address_space(1))) void*)(s + (size_t)i * 8 * KP),
                (__attribute__((address_space(3))) void*)(Ad + i * 512), 16, 0, 0);
    };
    auto stageB = [&](int buf, int T) {        // 3 instrs: wave's 24 B-rows (padded)
        bf16* Bd = &Bs[buf][wv * 24 * 64];
        const bf16* s = Bg + T * 64;
        #pragma unroll
        for (int c = 0; c < 3; c++)
            __builtin_amdgcn_global_load_lds(
                (const __attribute__((address_space(1))) void*)(s + (size_t)c * 8 * KP),
                (__attribute__((address_space(3))) void*)(Bd + c * 512), 16, 0, 0);
    };

    stageA(0, 0);
    stageB(0, 0);                              // 7 in flight

    for (int T = 0; T < NKT; T++) {
        int b = T & 1;
        const bf16* Ab = &As[b][0];
        const bf16* Bb = &Bs[b][0];
        // -------- phase A (k-half 0) --------
        if (T < NKT - 1) {
            stageA(b ^ 1, T + 1);              // 11 in flight
            asm volatile("s_waitcnt vmcnt(4)" ::: "memory");   // tile T's 7 landed
        } else {
            asm volatile("s_waitcnt vmcnt(0)" ::: "memory");   // final tile landed
        }
        __builtin_amdgcn_s_barrier();          // tile T visible to all waves
        asm volatile("" ::: "memory");
        {
            int sl = (q ^ (fr & 7)) * 8;
            s16x8 af0 = *(const s16x8*)(Ab + (wv * 32 + fr) * 64 + sl);
            s16x8 af1 = *(const s16x8*)(Ab + (wv * 32 + 16 + fr) * 64 + sl);
            s16x8 bfv[9];
            #pragma unroll
            for (int n2 = 0; n2 < 9; n2++)
                bfv[n2] = *(const s16x8*)(Bb + (n2 * 16 + fr) * 64 + sl);
            __builtin_amdgcn_s_setprio(1);
            #pragma unroll
            for (int n2 = 0; n2 < 9; n2++) {
                acc[0][n2] = __builtin_amdgcn_mfma_f32_16x16x32_bf16(af0, bfv[n2], acc[0][n2], 0, 0, 0);
                acc[1][n2] = __builtin_amdgcn_mfma_f32_16x16x32_bf16(af1, bfv[n2], acc[1][n2], 0, 0, 0);
            }
            __builtin_amdgcn_s_setprio(0);
        }
        // -------- phase B (k-half 1) --------
        if (T < NKT - 1) stageB(b ^ 1, T + 1);
        {
            int sl = ((4 + q) ^ (fr & 7)) * 8;
            s16x8 af0 = *(const s16x8*)(Ab + (wv * 32 + fr) * 64 + sl);
            s16x8 af1 = *(const s16x8*)(Ab + (wv * 32 + 16 + fr) * 64 + sl);
            s16x8 bfv[9];
            #pragma unroll
            for (int n2 = 0; n2 < 9; n2++)
                bfv[n2] = *(const s16x8*)(Bb + (n2 * 16 + fr) * 64 + sl);
            __builtin_amdgcn_s_setprio(1);
            #pragma unroll
            for (int n2 = 0; n2 < 9; n2++) {
                acc[0][n2] = __builtin_amdgcn_mfma_f32_16x16x32_bf16(af0, bfv[n2], acc[0][n2], 0, 0, 0);
                acc[1][n2] = __builtin_amdgcn_mfma_f32_16x16x32_bf16(af1, bfv[n2], acc[1][n2], 0, 0, 0);
            }
            __builtin_amdgcn_s_setprio(0);
        }
        asm volatile("s_waitcnt lgkmcnt(0)" ::: "memory");  // own reads of buf b done
        __builtin_amdgcn_sched_barrier(0);
        __builtin_amdgcn_s_barrier();          // all waves done reading buf b
        asm volatile("" ::: "memory");
    }

    int col = lane & 15, rowg = (lane >> 4) * 4;
    #pragma unroll
    for (int mt = 0; mt < 2; mt++)
        #pragma unroll
        for (int n2 = 0; n2 < 9; n2++)
            #pragma unroll
            for (int r = 0; r < 4; r++) {
                int gr = m0 + wv * 32 + mt * 16 + rowg + r;
                int gc = n0 + n2 * 16 + col;
                S[(size_t)gr * NP + gc] = __float2bfloat16(acc[mt][n2][r]);
            }
}

// ---------------- Epilogue: stage S rows as bf16 in LDS, contract j, 33x5 + sigmoid ----------
__global__ void __launch_bounds__(256) epilogue_kernel(const bf16* __restrict__ S,
                                const float* __restrict__ cd_h,
                                const float* __restrict__ bf1, const float* __restrict__ Wf2,
                                const float* __restrict__ bf2, float* __restrict__ out) {
    int w = threadIdx.x >> 6;
    int lane = threadIdx.x & 63;
    int b = blockIdx.x * 4 + w;
    __shared__ __align__(16) unsigned short Sl[4][1152];
    __shared__ float cdsh[4][33];
    __shared__ float hsh[4][40];
    const bf16* Srow = S + (size_t)b * NP;
    #pragma unroll
    for (int pass = 0; pass < 3; pass++) {
        int idx = lane + pass * 64;
        if (idx < 144)
            *(s16x8*)&Sl[w][idx * 8] = *(const s16x8*)(Srow + idx * 8);
    }
    if (lane == 0) cdsh[w][0] = 1.f;
    if (lane < 32) cdsh[w][lane + 1] = cd_h[(size_t)b * 32 + lane];
    __syncthreads();
    if (lane < 33) {
        float acc = bf1[lane];
        #pragma unroll 3
        for (int j = 0; j < 33; j++) {
            unsigned short sv = Sl[w][j * 33 + lane];
            acc += cdsh[w][j] * __bfloat162float(*(bf16*)&sv);
        }
        hsh[w][lane] = fmaxf(acc, 0.f);
    }
    __syncthreads();
    if (lane < 5) {
        float o = bf2[lane];
        for (int q = 0; q < 33; q++) o += hsh[w][q] * Wf2[q * 5 + lane];
        out[(size_t)b * 5 + lane] = 1.f / (1.f + expf(-o));
    }
}

extern "C" void kernel_launch(void* const* d_in, const int* in_sizes, int n_in,
                              void* d_out, int out_size, void* d_ws, size_t ws_size,
                              hipStream_t stream) {
    const float* US_x     = (const float*)d_in[0];
    const float* CDFI_x   = (const float*)d_in[1];
    const float* marker_x = (const float*)d_in[2];
    const float* Wf1      = (const float*)d_in[27];
    const float* bf1      = (const float*)d_in[28];
    const float* Wf2      = (const float*)d_in[29];
    const float* bf2      = (const float*)d_in[30];
    float* out = (float*)d_out;

    char* ws = (char*)d_ws;
    size_t off = 0;
    auto alloc = [&](size_t bytes) -> void* {
        void* p = ws + off;
        off = (off + bytes + 255) & ~(size_t)255;
        return p;
    };

    float* b1p_buf  = (float*)alloc(3 * 128 * sizeof(float));                 // zeroed
    float* pstat    = (float*)alloc((size_t)3 * SBLK * 2048 * sizeof(float)); // partials
    float* a_buf[3], *h_buf[3];
    for (int i = 0; i < 3; i++) {
        a_buf[i] = (float*)alloc(1024 * 4);
        h_buf[i] = (float*)alloc((size_t)NB * 32 * 4);
    }
    bf16*  p1   = (bf16*)alloc((size_t)NB * KP * 2);
    bf16*  W2t  = (bf16*)alloc((size_t)NP * KP * 2);
    bf16*  S    = (bf16*)alloc((size_t)NB * NP * 2);   // also absorbs B-pad OOB reads

    SubP3 P;
    const float* xs[3] = {US_x, CDFI_x, marker_x};
    int Fs[3] = {1024, 1024, 10};
    for (int i = 0; i < 3; i++) {
        int base = 3 + i * 8;
        P.s[i].x     = xs[i];
        P.s[i].gamma = (const float*)d_in[base + 0];
        P.s[i].beta  = (const float*)d_in[base + 1];
        P.s[i].W1    = (const float*)d_in[base + 2];
        P.s[i].b1    = (const float*)d_in[base + 3];
        P.s[i].W2    = (const float*)d_in[base + 4];
        P.s[i].b2    = (const float*)d_in[base + 5];
        P.s[i].W3    = (const float*)d_in[base + 6];
        P.s[i].b3    = (const float*)d_in[base + 7];
        P.s[i].sum   = pstat + (size_t)i * SBLK * 2048;
        P.s[i].sumsq = pstat + (size_t)i * SBLK * 2048 + 1024;
        P.s[i].b1p   = b1p_buf + i * 128;
        P.s[i].a     = a_buf[i];
        P.s[i].hout  = h_buf[i];
        P.s[i].F     = Fs[i];
    }

    float* us_h = h_buf[0];
    float* cd_h = h_buf[1];
    float* mk_h = h_buf[2];

    hipMemsetAsync(b1p_buf, 0, 3 * 128 * sizeof(float), stream);

    stats3_kernel<<<dim3(SBLK, 1, 3), 256, 0, stream>>>(P);
    prep3_kernel<<<dim3(32, 3), 256, 0, stream>>>(P);
    subnet3_kernel<<<dim3(256, 3), 256, 0, stream>>>(P);

    build_both<<<NB / 4 + 1089, 256, 0, stream>>>(mk_h, us_h, p1, Wf1, W2t);

    gemm_kernel<<<dim3(NB / 256, NP / 144), 512, 0, stream>>>(p1, W2t, S);

    epilogue_kernel<<<NB / 4, 256, 0, stream>>>(S, cd_h, bf1, Wf2, bf2, out);
}

// Round 10
// 237.346 us; speedup vs baseline: 1.3557x; 1.0380x over previous
//
#include <hip/hip_runtime.h>
#include <hip/hip_bf16.h>
#include <math.h>

typedef __hip_bfloat16 bf16;
typedef __attribute__((ext_vector_type(4))) float f32x4;
typedef __attribute__((ext_vector_type(8))) short s16x8;

#define NB 8192
#define KP 1152   // padded K: 1089 -> 18*64
#define NP 1152   // padded N: 1089 -> 8*144
#define NKT 18    // K-tiles of 64
#define SBLK 256  // stats blocks per subnet (32 rows each)

struct SubP {
    const float* x; const float* gamma; const float* beta;
    const float* W1; const float* b1; const float* W2; const float* b2;
    const float* W3; const float* b3;
    float* sum; float* sumsq; float* a; float* b1p; float* hout;
    bf16* w1t;    // [32][1024] bf16: W1t[h][k] = a[k]*W1[k][h] (heavy subnets only)
    int F;
};
struct SubP3 { SubP s[3]; };

// ---------------- BatchNorm stats: 32 rows/block, grid (256,3), contention-free ----------
__global__ void __launch_bounds__(256) stats3_kernel(SubP3 P) {
    const SubP p = P.s[blockIdx.z];
    int t = threadIdx.x;
    int blk = blockIdx.x;
    int row0 = blk * 32;
    if (p.F == 1024) {
        f32x4 s = {0.f, 0.f, 0.f, 0.f}, s2 = {0.f, 0.f, 0.f, 0.f};
        const float* xp = p.x + (size_t)row0 * 1024 + t * 4;
        #pragma unroll 8
        for (int r = 0; r < 32; r++) {
            f32x4 v = *(const f32x4*)(xp + (size_t)r * 1024);
            s += v; s2 += v * v;
        }
        int f = t * 4;
        *(f32x4*)&p.sum[(size_t)blk * 2048 + f]   = s;
        *(f32x4*)&p.sumsq[(size_t)blk * 2048 + f] = s2;
    } else {
        __shared__ float ls[16], ls2[16];
        if (t < 16) { ls[t] = 0.f; ls2[t] = 0.f; }
        __syncthreads();
        int F = p.F;
        for (int idx = t; idx < 32 * F; idx += 256) {
            float v = p.x[(size_t)row0 * F + idx];
            int f = idx % 10;            // row0*F = blk*320 ≡ 0 (mod 10)
            atomicAdd(&ls[f], v);        // LDS-scope only
            atomicAdd(&ls2[f], v * v);
        }
        __syncthreads();
        if (t < F) {
            p.sum[(size_t)blk * 2048 + t]   = ls[t];
            p.sumsq[(size_t)blk * 2048 + t] = ls2[t];
        }
    }
}

// ---------------- finalize stats: reduce partials; a[f]; c@W1 -> b1p; W1t bf16 build ----
__global__ void prep3_kernel(SubP3 P) {
    const SubP p = P.s[blockIdx.y];
    int f0 = blockIdx.x * 32;
    if (f0 >= p.F) return;
    int t = threadIdx.x;
    __shared__ float c_sh[32];
    __shared__ float ash[32];
    __shared__ float red[8][33];
    __shared__ float rs[8][33], rs2[8][33];
    int fc = p.F - f0; if (fc > 32) fc = 32;
    int fi = t & 31, g = t >> 5;
    {
        float s = 0.f, s2 = 0.f;
        if (fi < fc) {
            for (int blk = g; blk < SBLK; blk += 8) {
                s  += p.sum[(size_t)blk * 2048 + f0 + fi];
                s2 += p.sumsq[(size_t)blk * 2048 + f0 + fi];
            }
        }
        rs[g][fi] = s; rs2[g][fi] = s2;
    }
    __syncthreads();
    if (t < 32) {
        float c = 0.f, av = 0.f;
        if (t < fc) {
            float sm = 0.f, sq = 0.f;
            #pragma unroll
            for (int gg = 0; gg < 8; gg++) { sm += rs[gg][t]; sq += rs2[gg][t]; }
            int f = f0 + t;
            float mu  = sm * (1.f / 8192.f);
            float var = sq * (1.f / 8192.f) - mu * mu;
            av = p.gamma[f] * rsqrtf(var + 1e-5f);
            p.a[f] = av;
            c = p.beta[f] - mu * av;
        }
        c_sh[t] = c; ash[t] = av;
    }
    __syncthreads();
    int h = t & 31; g = t >> 5;
    float s = 0.f;
    for (int fi2 = g; fi2 < fc; fi2 += 8)
        s += c_sh[fi2] * p.W1[(size_t)(f0 + fi2) * 32 + h];
    red[g][h] = s;
    __syncthreads();
    if (t < 32) {
        float tot = 0.f;
        #pragma unroll
        for (int gg = 0; gg < 8; gg++) tot += red[gg][t];
        atomicAdd(&p.b1p[t], tot);
    }
    // W1t build (heavy subnets): W1t[h][k] = a[k]*W1[k][h], bf16, stride 1024
    if (p.F == 1024) {
        for (int idx = t; idx < 1024; idx += 256) {
            int kk = idx >> 5, hh = idx & 31;
            p.w1t[(size_t)hh * 1024 + f0 + kk] =
                __float2bfloat16(ash[kk] * p.W1[(size_t)(f0 + kk) * 32 + hh]);
        }
    }
}

// ---------------- Subnet MLP: 32 rows/block; heavy layer-1 via bf16 MFMA ----------------
// R9 post-mortem: subnet3 was the top dispatch (48us, MfmaUtil 0, VALUBusy 20%) --
// a K=1024 matmul running on the fp32 VALU (Common-mistake: matmul-shaped compute
// without matrix cores). Heavy path now: per 128-k chunk stage X (fp32->bf16,
// XOR-swizzled reg-staged writes, rule 21) + W1t into LDS; each of 4 waves runs its
// 32-k MFMA step (2m x 2n frags, C-layout verified in main GEMM); k-split merged via
// Red. bf16 rounding of X/W1 ~ same magnitude as the accepted p1/W2t rounding.
// Layers 2/3 (32x32, tiny) stay fp32 and are shared with the marker path.
__global__ void __launch_bounds__(256) subnet3_kernel(SubP3 P) {
    const SubP p = P.s[blockIdx.y];
    const int F = p.F;
    __shared__ float smem[9760];
    float* Red = smem;            // 3 x 1152
    float* H1  = smem + 3456;     // [32][36]
    float* W23 = smem + 4608;     // [32][33] (pad to 5664)
    float* H2  = smem;            // reuse

    int t = threadIdx.x;
    int row0 = blockIdx.x * 32;
    int kg = t >> 6;
    int lane = t & 63;
    int hg = lane & 7, h0 = hg * 4;
    int rg = (lane >> 3) & 3;
    int ks = lane >> 5;

    if (F == 1024) {
        bf16* Xl = (bf16*)(smem + 5664);   // [32][128] bf16, swizzled (8 KB)
        bf16* Wl = (bf16*)(smem + 7712);   // [32][128] bf16, swizzled (8 KB)
        int xr = t >> 3, xc = (t & 7) * 16;
        int sw = xr & 7;
        int s0 = ((t & 7) * 2) ^ sw, s1 = ((t & 7) * 2 + 1) ^ sw;
        const float* xbase = p.x + (size_t)(row0 + xr) * 1024 + xc;
        const bf16*  wbase = p.w1t + (size_t)xr * 1024 + xc;
        f32x4 xp[4]; s16x8 wp0, wp1;
        #pragma unroll
        for (int i = 0; i < 4; i++) xp[i] = *(const f32x4*)(xbase + i * 4);
        wp0 = *(const s16x8*)(wbase);
        wp1 = *(const s16x8*)(wbase + 8);

        f32x4 acc[2][2] = {};
        int fr = lane & 15, qq = lane >> 4;
        int rsw0 = fr & 7;                 // read-side XOR (rows fr and 16+fr: same &7)

        for (int c = 0; c < 8; c++) {
            __builtin_amdgcn_s_barrier();           // prev chunk's LDS reads done
            asm volatile("" ::: "memory");
            {   // pack fp32 -> bf16, swizzled LDS writes
                s16x8 v0, v1;
                #pragma unroll
                for (int i = 0; i < 2; i++)
                    #pragma unroll
                    for (int e = 0; e < 4; e++) {
                        __hip_bfloat16 hb = __float2bfloat16(xp[i][e]);
                        v0[i * 4 + e] = *(short*)&hb;
                    }
                #pragma unroll
                for (int i = 0; i < 2; i++)
                    #pragma unroll
                    for (int e = 0; e < 4; e++) {
                        __hip_bfloat16 hb = __float2bfloat16(xp[2 + i][e]);
                        v1[i * 4 + e] = *(short*)&hb;
                    }
                *(s16x8*)((char*)Xl + xr * 256 + s0 * 16) = v0;
                *(s16x8*)((char*)Xl + xr * 256 + s1 * 16) = v1;
                *(s16x8*)((char*)Wl + xr * 256 + s0 * 16) = wp0;
                *(s16x8*)((char*)Wl + xr * 256 + s1 * 16) = wp1;
            }
            if (c < 7) {                            // prefetch next chunk into regs
                int k0 = (c + 1) * 128;
                #pragma unroll
                for (int i = 0; i < 4; i++) xp[i] = *(const f32x4*)(xbase + k0 + i * 4);
                wp0 = *(const s16x8*)(wbase + k0);
                wp1 = *(const s16x8*)(wbase + k0 + 8);
            }
            asm volatile("s_waitcnt lgkmcnt(0)" ::: "memory");  // own LDS writes done
            __builtin_amdgcn_sched_barrier(0);
            __builtin_amdgcn_s_barrier();           // tiles visible; vmcnt NOT drained
            asm volatile("" ::: "memory");
            {   // wave kg computes its 32-k step: slots kq..kq+3, lane slot = kq+qq
                int sx = kg * 4 + qq;
                int sl = (sx ^ rsw0) * 16;
                s16x8 a0 = *(const s16x8*)((char*)Xl + fr * 256 + sl);
                s16x8 a1 = *(const s16x8*)((char*)Xl + (16 + fr) * 256 + sl);
                s16x8 b0 = *(const s16x8*)((char*)Wl + fr * 256 + sl);
                s16x8 b1 = *(const s16x8*)((char*)Wl + (16 + fr) * 256 + sl);
                acc[0][0] = __builtin_amdgcn_mfma_f32_16x16x32_bf16(a0, b0, acc[0][0], 0, 0, 0);
                acc[0][1] = __builtin_amdgcn_mfma_f32_16x16x32_bf16(a0, b1, acc[0][1], 0, 0, 0);
                acc[1][0] = __builtin_amdgcn_mfma_f32_16x16x32_bf16(a1, b0, acc[1][0], 0, 0, 0);
                acc[1][1] = __builtin_amdgcn_mfma_f32_16x16x32_bf16(a1, b1, acc[1][1], 0, 0, 0);
            }
        }
        // k-split merge via Red (Red region disjoint from Xl/Wl)
        int col = lane & 15, rowg = (lane >> 4) * 4;
        if (kg > 0) {
            #pragma unroll
            for (int m = 0; m < 2; m++)
                #pragma unroll
                for (int n = 0; n < 2; n++)
                    #pragma unroll
                    for (int r = 0; r < 4; r++)
                        Red[(kg - 1) * 1152 + (m * 16 + rowg + r) * 36 + n * 16 + col] = acc[m][n][r];
        }
        __syncthreads();                            // Red ready (full drain: safe)
        if (kg == 0) {
            #pragma unroll
            for (int m = 0; m < 2; m++)
                #pragma unroll
                for (int n = 0; n < 2; n++) {
                    int cc = n * 16 + col;
                    float bv = p.b1[cc] + p.b1p[cc];
                    #pragma unroll
                    for (int r = 0; r < 4; r++) {
                        int rr = m * 16 + rowg + r;
                        float v = acc[m][n][r] + bv;
                        #pragma unroll
                        for (int pp = 0; pp < 3; pp++)
                            v += Red[pp * 1152 + rr * 36 + cc];
                        H1[rr * 36 + cc] = fmaxf(v, 0.f);
                    }
                }
        }
    } else {
        float* Xt = smem;             // [32][68]
        float* Wt = smem + 2176;      // [64][36]
        float acc[4][8] = {};         // [hi][ri], rows rg + 4*ri
        int kbase = (kg * 2 + ks) * 8;
        for (int k0 = 0; k0 < F; k0 += 64) {
            int kc = F - k0; if (kc > 64) kc = 64;
            int kcp = (kc + 3) & ~3;
            __syncthreads();
            for (int idx = t; idx < 32 * kcp; idx += 256) {
                int r = idx / kcp, kk = idx - r * kcp;
                Xt[r * 68 + kk] = (kk < kc) ? p.x[(size_t)(row0 + r) * F + k0 + kk] : 0.f;
            }
            for (int idx = t; idx < kcp * 32; idx += 256) {
                int kk = idx >> 5, hh = idx & 31;
                Wt[kk * 36 + hh] = (kk < kc) ? p.a[k0 + kk] * p.W1[(size_t)(k0 + kk) * 32 + hh] : 0.f;
            }
            __syncthreads();
            #pragma unroll
            for (int s = 0; s < 2; s++) {
                int kk = kbase + s * 4;
                if (kk < kcp) {
                    f32x4 wv[4], xv[8];
                    #pragma unroll
                    for (int j = 0; j < 4; j++)  wv[j]  = *(const f32x4*)&Wt[(kk + j) * 36 + h0];
                    #pragma unroll
                    for (int ri = 0; ri < 8; ri++) xv[ri] = *(const f32x4*)&Xt[(rg + 4 * ri) * 68 + kk];
                    #pragma unroll
                    for (int j = 0; j < 4; j++)
                        #pragma unroll
                        for (int hi = 0; hi < 4; hi++) {
                            float w = wv[j][hi];
                            #pragma unroll
                            for (int ri = 0; ri < 8; ri++)
                                acc[hi][ri] = fmaf(w, xv[ri][j], acc[hi][ri]);
                        }
                }
            }
        }
        // merge the two lane-half k-slices in-register
        #pragma unroll
        for (int hi = 0; hi < 4; hi++)
            #pragma unroll
            for (int ri = 0; ri < 8; ri++)
                acc[hi][ri] += __shfl_xor(acc[hi][ri], 32);
        __syncthreads();                              // Xt/Wt dead
        if (kg > 0 && ks == 0) {
            #pragma unroll
            for (int ri = 0; ri < 8; ri++) {
                int r = rg + 4 * ri;
                f32x4 v = {acc[0][ri], acc[1][ri], acc[2][ri], acc[3][ri]};
                *(f32x4*)&Red[(kg - 1) * 1152 + r * 36 + h0] = v;
            }
        }
        __syncthreads();                              // Red ready
        if (kg == 0 && ks == 0) {
            f32x4 b;
            #pragma unroll
            for (int hi = 0; hi < 4; hi++) b[hi] = p.b1[h0 + hi] + p.b1p[h0 + hi];
            #pragma unroll
            for (int ri = 0; ri < 8; ri++) {
                int r = rg + 4 * ri;
                f32x4 v = {acc[0][ri], acc[1][ri], acc[2][ri], acc[3][ri]};
                #pragma unroll
                for (int pp = 0; pp < 3; pp++)
                    v += *(const f32x4*)&Red[pp * 1152 + r * 36 + h0];
                v += b;
                #pragma unroll
                for (int hi = 0; hi < 4; hi++)
                    H1[r * 36 + h0 + hi] = fmaxf(v[hi], 0.f);
            }
        }
    }
    // -------- shared fp32 layers 2/3 (32 rows) --------
    for (int idx = t; idx < 1024; idx += 256) W23[(idx >> 5) * 33 + (idx & 31)] = p.W2[idx];
    __syncthreads();                              // H1 + W23 ready
    int h = t & 31, rq = t >> 5;                  // 8 groups x 4 rows
    {
        float a2[4] = {};
        for (int q = 0; q < 32; q++) {
            float w = W23[q * 33 + h];
            #pragma unroll
            for (int i = 0; i < 4; i++) a2[i] += H1[(rq * 4 + i) * 36 + q] * w;
        }
        float bv = p.b2[h];
        #pragma unroll
        for (int i = 0; i < 4; i++) H2[(rq * 4 + i) * 36 + h] = fmaxf(a2[i] + bv, 0.f);
    }
    __syncthreads();
    for (int idx = t; idx < 1024; idx += 256) W23[(idx >> 5) * 33 + (idx & 31)] = p.W3[idx];
    __syncthreads();
    {
        float a3[4] = {};
        for (int q = 0; q < 32; q++) {
            float w = W23[q * 33 + h];
            #pragma unroll
            for (int i = 0; i < 4; i++) a3[i] += H2[(rq * 4 + i) * 36 + q] * w;
        }
        float bv = p.b3[h];
        #pragma unroll
        for (int i = 0; i < 4; i++)
            p.hout[(size_t)(row0 + rq * 4 + i) * 32 + h] = fmaxf(a3[i] + bv, 0.f);
    }
}

// ---------------- p1 build (4 rows/block, wave-per-row) + W2t transpose, one launch -------
__global__ void __launch_bounds__(256) build_both(const float* __restrict__ mk_h,
                           const float* __restrict__ us_h,
                           bf16* __restrict__ p1,
                           const float* __restrict__ Wf1, bf16* __restrict__ W2t) {
    int blk = blockIdx.x;
    int t = threadIdx.x;
    if (blk < NB / 4) {
        int r = t >> 6, lane = t & 63;
        int b = blk * 4 + r;
        __shared__ float mk1[4][34], us1[4][34];
        if (lane == 0) { mk1[r][0] = 1.f; us1[r][0] = 1.f; }
        if (lane < 32) mk1[r][lane + 1] = mk_h[(size_t)b * 32 + lane];
        else           us1[r][lane - 31] = us_h[(size_t)b * 32 + (lane - 32)];
        __syncthreads();
        #pragma unroll
        for (int c = 0; c < 3; c++) {
            int chunk = lane + 64 * c;
            if (chunk < 144) {                 // 144*8 = 1152 = KP
                int base = chunk * 8;
                s16x8 v;
                #pragma unroll
                for (int e = 0; e < 8; e++) {
                    int idx = base + e;
                    float val = 0.f;
                    if (idx < 1089) {
                        int k = idx / 33, i = idx - k * 33;
                        val = mk1[r][k] * us1[r][i];
                    }
                    __hip_bfloat16 hb = __float2bfloat16(val);
                    v[e] = *(short*)&hb;
                }
                *(s16x8*)(p1 + (size_t)b * KP + base) = v;
            }
        }
    } else {
        int kj = blk - NB / 4;
        int k = kj / 33, j = kj - k * 33;
        __shared__ float tile[1089];
        const float* src = Wf1 + (size_t)k * 35937 + (size_t)j * 1089;  // [i][o] contiguous
        for (int idx = t; idx < 1089; idx += 256) tile[idx] = src[idx];
        __syncthreads();
        for (int idx = t; idx < 1089; idx += 256) {
            int o = idx / 33, i = idx - o * 33;
            W2t[(size_t)(j * 33 + o) * KP + k * 33 + i] = __float2bfloat16(tile[i * 33 + o]);
        }
        if (k == 0) {
            bf16 z = __float2bfloat16(0.f);
            for (int idx = t; idx < 33 * 63; idx += 256) {
                int o = idx / 63, kkp = 1089 + idx - o * 63;
                W2t[(size_t)(j * 33 + o) * KP + kkp] = z;
            }
        }
    }
}

// ---------------- Main GEMM: R9 8-phase-family (verified best) -- FROZEN ----------------
__global__ void __launch_bounds__(512) gemm_kernel(const bf16* __restrict__ A,   // [NB][KP]
                                                   const bf16* __restrict__ Bt,  // [NP][KP]
                                                   bf16* __restrict__ S) {       // [NB][NP]
    __shared__ __align__(16) bf16 As[2][256 * 64];   // 64 KB
    __shared__ __align__(16) bf16 Bs[2][192 * 64];   // 48 KB (rows 144..191 = pad)
    int t = threadIdx.x;
    int wv = t >> 6, lane = t & 63;
    int m0 = blockIdx.x * 256;
    int n0 = blockIdx.y * 144;
    int fr = lane & 15;
    int q  = lane >> 4;
    int lr8 = lane >> 3;
    int sslot = (lane & 7) ^ lr8;

    const bf16* Ag = A  + (size_t)(m0 + wv * 32 + lr8) * KP + sslot * 8;
    const bf16* Bg = Bt + (size_t)(n0 + wv * 24 + lr8) * KP + sslot * 8;

    f32x4 acc[2][9] = {};

    auto stageA = [&](int buf, int T) {
        bf16* Ad = &As[buf][wv * 32 * 64];
        const bf16* s = Ag + T * 64;
        #pragma unroll
        for (int i = 0; i < 4; i++)
            __builtin_amdgcn_global_load_lds(
                (const __attribute__((address_space(1))) void*)(s + (size_t)i * 8 * KP),
                (__attribute__((address_space(3))) void*)(Ad + i * 512), 16, 0, 0);
    };
    auto stageB = [&](int buf, int T) {
        bf16* Bd = &Bs[buf][wv * 24 * 64];
        const bf16* s = Bg + T * 64;
        #pragma unroll
        for (int c = 0; c < 3; c++)
            __builtin_amdgcn_global_load_lds(
                (const __attribute__((address_space(1))) void*)(s + (size_t)c * 8 * KP),
                (__attribute__((address_space(3))) void*)(Bd + c * 512), 16, 0, 0);
    };

    stageA(0, 0);
    stageB(0, 0);

    for (int T = 0; T < NKT; T++) {
        int b = T & 1;
        const bf16* Ab = &As[b][0];
        const bf16* Bb = &Bs[b][0];
        if (T < NKT - 1) {
            stageA(b ^ 1, T + 1);
            asm volatile("s_waitcnt vmcnt(4)" ::: "memory");
        } else {
            asm volatile("s_waitcnt vmcnt(0)" ::: "memory");
        }
        __builtin_amdgcn_s_barrier();
        asm volatile("" ::: "memory");
        {
            int sl = (q ^ (fr & 7)) * 8;
            s16x8 af0 = *(const s16x8*)(Ab + (wv * 32 + fr) * 64 + sl);
            s16x8 af1 = *(const s16x8*)(Ab + (wv * 32 + 16 + fr) * 64 + sl);
            s16x8 bfv[9];
            #pragma unroll
            for (int n2 = 0; n2 < 9; n2++)
                bfv[n2] = *(const s16x8*)(Bb + (n2 * 16 + fr) * 64 + sl);
            __builtin_amdgcn_s_setprio(1);
            #pragma unroll
            for (int n2 = 0; n2 < 9; n2++) {
                acc[0][n2] = __builtin_amdgcn_mfma_f32_16x16x32_bf16(af0, bfv[n2], acc[0][n2], 0, 0, 0);
                acc[1][n2] = __builtin_amdgcn_mfma_f32_16x16x32_bf16(af1, bfv[n2], acc[1][n2], 0, 0, 0);
            }
            __builtin_amdgcn_s_setprio(0);
        }
        if (T < NKT - 1) stageB(b ^ 1, T + 1);
        {
            int sl = ((4 + q) ^ (fr & 7)) * 8;
            s16x8 af0 = *(const s16x8*)(Ab + (wv * 32 + fr) * 64 + sl);
            s16x8 af1 = *(const s16x8*)(Ab + (wv * 32 + 16 + fr) * 64 + sl);
            s16x8 bfv[9];
            #pragma unroll
            for (int n2 = 0; n2 < 9; n2++)
                bfv[n2] = *(const s16x8*)(Bb + (n2 * 16 + fr) * 64 + sl);
            __builtin_amdgcn_s_setprio(1);
            #pragma unroll
            for (int n2 = 0; n2 < 9; n2++) {
                acc[0][n2] = __builtin_amdgcn_mfma_f32_16x16x32_bf16(af0, bfv[n2], acc[0][n2], 0, 0, 0);
                acc[1][n2] = __builtin_amdgcn_mfma_f32_16x16x32_bf16(af1, bfv[n2], acc[1][n2], 0, 0, 0);
            }
            __builtin_amdgcn_s_setprio(0);
        }
        asm volatile("s_waitcnt lgkmcnt(0)" ::: "memory");
        __builtin_amdgcn_sched_barrier(0);
        __builtin_amdgcn_s_barrier();
        asm volatile("" ::: "memory");
    }

    int col = lane & 15, rowg = (lane >> 4) * 4;
    #pragma unroll
    for (int mt = 0; mt < 2; mt++)
        #pragma unroll
        for (int n2 = 0; n2 < 9; n2++)
            #pragma unroll
            for (int r = 0; r < 4; r++) {
                int gr = m0 + wv * 32 + mt * 16 + rowg + r;
                int gc = n0 + n2 * 16 + col;
                S[(size_t)gr * NP + gc] = __float2bfloat16(acc[mt][n2][r]);
            }
}

// ---------------- Epilogue: stage S rows as bf16 in LDS, contract j, 33x5 + sigmoid ----------
__global__ void __launch_bounds__(256) epilogue_kernel(const bf16* __restrict__ S,
                                const float* __restrict__ cd_h,
                                const float* __restrict__ bf1, const float* __restrict__ Wf2,
                                const float* __restrict__ bf2, float* __restrict__ out) {
    int w = threadIdx.x >> 6;
    int lane = threadIdx.x & 63;
    int b = blockIdx.x * 4 + w;
    __shared__ __align__(16) unsigned short Sl[4][1152];
    __shared__ float cdsh[4][33];
    __shared__ float hsh[4][40];
    const bf16* Srow = S + (size_t)b * NP;
    #pragma unroll
    for (int pass = 0; pass < 3; pass++) {
        int idx = lane + pass * 64;
        if (idx < 144)
            *(s16x8*)&Sl[w][idx * 8] = *(const s16x8*)(Srow + idx * 8);
    }
    if (lane == 0) cdsh[w][0] = 1.f;
    if (lane < 32) cdsh[w][lane + 1] = cd_h[(size_t)b * 32 + lane];
    __syncthreads();
    if (lane < 33) {
        float acc = bf1[lane];
        #pragma unroll 3
        for (int j = 0; j < 33; j++) {
            unsigned short sv = Sl[w][j * 33 + lane];
            acc += cdsh[w][j] * __bfloat162float(*(bf16*)&sv);
        }
        hsh[w][lane] = fmaxf(acc, 0.f);
    }
    __syncthreads();
    if (lane < 5) {
        float o = bf2[lane];
        for (int q = 0; q < 33; q++) o += hsh[w][q] * Wf2[q * 5 + lane];
        out[(size_t)b * 5 + lane] = 1.f / (1.f + expf(-o));
    }
}

extern "C" void kernel_launch(void* const* d_in, const int* in_sizes, int n_in,
                              void* d_out, int out_size, void* d_ws, size_t ws_size,
                              hipStream_t stream) {
    const float* US_x     = (const float*)d_in[0];
    const float* CDFI_x   = (const float*)d_in[1];
    const float* marker_x = (const float*)d_in[2];
    const float* Wf1      = (const float*)d_in[27];
    const float* bf1      = (const float*)d_in[28];
    const float* Wf2      = (const float*)d_in[29];
    const float* bf2      = (const float*)d_in[30];
    float* out = (float*)d_out;

    char* ws = (char*)d_ws;
    size_t off = 0;
    auto alloc = [&](size_t bytes) -> void* {
        void* p = ws + off;
        off = (off + bytes + 255) & ~(size_t)255;
        return p;
    };

    float* b1p_buf  = (float*)alloc(3 * 128 * sizeof(float));                 // zeroed
    float* pstat    = (float*)alloc((size_t)3 * SBLK * 2048 * sizeof(float)); // partials
    bf16*  w1t_buf  = (bf16*)alloc((size_t)3 * 32 * 1024 * 2);                // W1t per subnet
    float* a_buf[3], *h_buf[3];
    for (int i = 0; i < 3; i++) {
        a_buf[i] = (float*)alloc(1024 * 4);
        h_buf[i] = (float*)alloc((size_t)NB * 32 * 4);
    }
    bf16*  p1   = (bf16*)alloc((size_t)NB * KP * 2);
    bf16*  W2t  = (bf16*)alloc((size_t)NP * KP * 2);
    bf16*  S    = (bf16*)alloc((size_t)NB * NP * 2);

    SubP3 P;
    const float* xs[3] = {US_x, CDFI_x, marker_x};
    int Fs[3] = {1024, 1024, 10};
    for (int i = 0; i < 3; i++) {
        int base = 3 + i * 8;
        P.s[i].x     = xs[i];
        P.s[i].gamma = (const float*)d_in[base + 0];
        P.s[i].beta  = (const float*)d_in[base + 1];
        P.s[i].W1    = (const float*)d_in[base + 2];
        P.s[i].b1    = (const float*)d_in[base + 3];
        P.s[i].W2    = (const float*)d_in[base + 4];
        P.s[i].b2    = (const float*)d_in[base + 5];
        P.s[i].W3    = (const float*)d_in[base + 6];
        P.s[i].b3    = (const float*)d_in[base + 7];
        P.s[i].sum   = pstat + (size_t)i * SBLK * 2048;
        P.s[i].sumsq = pstat + (size_t)i * SBLK * 2048 + 1024;
        P.s[i].b1p   = b1p_buf + i * 128;
        P.s[i].a     = a_buf[i];
        P.s[i].hout  = h_buf[i];
        P.s[i].w1t   = w1t_buf + (size_t)i * 32 * 1024;
        P.s[i].F     = Fs[i];
    }

    float* us_h = h_buf[0];
    float* cd_h = h_buf[1];
    float* mk_h = h_buf[2];

    hipMemsetAsync(b1p_buf, 0, 3 * 128 * sizeof(float), stream);

    stats3_kernel<<<dim3(SBLK, 1, 3), 256, 0, stream>>>(P);
    prep3_kernel<<<dim3(32, 3), 256, 0, stream>>>(P);
    subnet3_kernel<<<dim3(256, 3), 256, 0, stream>>>(P);

    build_both<<<NB / 4 + 1089, 256, 0, stream>>>(mk_h, us_h, p1, Wf1, W2t);

    gemm_kernel<<<dim3(NB / 256, NP / 144), 512, 0, stream>>>(p1, W2t, S);

    epilogue_kernel<<<NB / 4, 256, 0, stream>>>(S, cd_h, bf1, Wf2, bf2, out);
}